// Round 6
// baseline (519.757 us; speedup 1.0000x reference)
//
#include <hip/hip_runtime.h>
#include <math.h>

#define F_IN 256
#define HID  64
#define BSH  8              // bucket = dst >> 8 (256 nodes per bucket)
#define BSPAN 256
#define CHUNK 4096          // edges per sort block (16 per thread)
#define NBK_MAX 512

typedef __bf16   bf16x8 __attribute__((ext_vector_type(8)));
typedef float    floatx4 __attribute__((ext_vector_type(4)));
typedef _Float16 half8 __attribute__((ext_vector_type(8)));

// ---------------------------------------------------------------------------
// Pass 1: per-chunk histogram over coarse dst buckets
// ---------------------------------------------------------------------------
__global__ __launch_bounds__(256) void k_hist(const int* __restrict__ dst,
                                              int* __restrict__ cntT,
                                              int E, int NCH, int NBK) {
    __shared__ int hist[NBK_MAX];
    int t = threadIdx.x, c = blockIdx.x;
    hist[t] = 0; hist[t + 256] = 0;
    __syncthreads();
    int base = c * CHUNK;
#pragma unroll 4
    for (int j = 0; j < CHUNK / 256; j++) {
        int e = base + j * 256 + t;
        if (e < E) atomicAdd(&hist[dst[e] >> BSH], 1);
    }
    __syncthreads();
    for (int b = t; b < NBK; b += 256) cntT[b * NCH + c] = hist[b];
}

// ---------------------------------------------------------------------------
// Exclusive scan of cntT (S elements) -> off, plus sentinel off[S] = total
// ---------------------------------------------------------------------------
__global__ __launch_bounds__(256) void k_scanA(const int* __restrict__ cntT,
                                               int* __restrict__ off,
                                               int* __restrict__ partials, int S) {
    __shared__ int sh[256];
    int tid = threadIdx.x;
    int base = blockIdx.x * 1024 + tid * 4;
    int v[4];
    int s = 0;
#pragma unroll
    for (int j = 0; j < 4; j++) {
        int idx = base + j;
        v[j] = (idx < S) ? cntT[idx] : 0;
        s += v[j];
    }
    sh[tid] = s;
    __syncthreads();
    int mysum = s;
    for (int o = 1; o < 256; o <<= 1) {
        int tv = (tid >= o) ? sh[tid - o] : 0;
        __syncthreads();
        sh[tid] += tv;
        __syncthreads();
    }
    int pref = sh[tid] - mysum;
#pragma unroll
    for (int j = 0; j < 4; j++) {
        int idx = base + j;
        if (idx < S) off[idx] = pref;
        pref += v[j];
    }
    if (tid == 255) partials[blockIdx.x] = sh[255];
}

__global__ void k_scanB(int* __restrict__ partials, int* __restrict__ off,
                        int nblk, int S) {
    if (blockIdx.x == 0 && threadIdx.x == 0) {
        int run = 0;
        for (int b = 0; b < nblk; b++) { int t = partials[b]; partials[b] = run; run += t; }
        off[S] = run;   // == E
    }
}

__global__ void k_scanC(int* __restrict__ off, const int* __restrict__ partials, int S) {
    int i = blockIdx.x * blockDim.x + threadIdx.x;
    if (i < S) off[i] += partials[i >> 10];
}

// ---------------------------------------------------------------------------
// Pass 2: scatter edges into bucket-grouped ebuf. Entry = (src<<8)|(dst&255)
// ---------------------------------------------------------------------------
__global__ __launch_bounds__(256) void k_sortwrite(const int* __restrict__ src,
                                                   const int* __restrict__ dst,
                                                   const int* __restrict__ off,
                                                   int* __restrict__ ebuf,
                                                   int E, int NCH, int NBK) {
    __shared__ int cur[NBK_MAX];
    int t = threadIdx.x, c = blockIdx.x;
    for (int b = t; b < NBK; b += 256) cur[b] = off[b * NCH + c];
    __syncthreads();
    int base = c * CHUNK;
#pragma unroll 4
    for (int j = 0; j < CHUNK / 256; j++) {
        int e = base + j * 256 + t;
        if (e < E) {
            int s = src[e];
            int d = dst[e];
            int pos = atomicAdd(&cur[d >> BSH], 1);
            ebuf[pos] = (s << BSH) | (d & (BSPAN - 1));
        }
    }
}

// ---------------------------------------------------------------------------
// Pass 3: per-bucket node-level CSR: rp, dinv, node-sorted esrc (+pad)
//   esrc entry = (src << 6) | (dst & 63)  — dst-local row for 64-node agg blk
// ---------------------------------------------------------------------------
__global__ __launch_bounds__(256) void k_bucket_csr(const int* __restrict__ off,
                                                    const int* __restrict__ ebuf,
                                                    int* __restrict__ rp,
                                                    float* __restrict__ dinv,
                                                    int* __restrict__ esrc,
                                                    int N, int NCH, int NBK) {
    __shared__ int cnt[BSPAN];
    __shared__ int sh[BSPAN];
    int b = blockIdx.x, t = threadIdx.x;
    int base = off[b * NCH];
    int end  = off[(b + 1) * NCH];

    cnt[t] = 0;
    __syncthreads();
    for (int i = base + t; i < end; i += 256) atomicAdd(&cnt[ebuf[i] & (BSPAN - 1)], 1);
    __syncthreads();

    int c = cnt[t];
    sh[t] = c;
    __syncthreads();
    for (int o = 1; o < 256; o <<= 1) {
        int tv = (t >= o) ? sh[t - o] : 0;
        __syncthreads();
        sh[t] += tv;
        __syncthreads();
    }
    int excl = sh[t] - c;

    int node = (b << BSH) + t;
    if (node < N) {
        rp[node] = base + excl;
        dinv[node] = rsqrtf((float)(1 + c));
    }
    if (b == NBK - 1) {
        if (t == 0) rp[N] = end;
        if (t < 16) esrc[end + t] = 0;     // pad: safe entries for tail loads
    }
    __syncthreads();

    cnt[t] = base + excl;
    __syncthreads();
    for (int i = base + t; i < end; i += 256) {
        int v = ebuf[i];
        int p = atomicAdd(&cnt[v & (BSPAN - 1)], 1);
        esrc[p] = ((v >> BSH) << 6) | (v & 63);   // (src<<6)|row64
    }
}

// ---------------------------------------------------------------------------
// Weight prep: W[K x 64] -> split-bf16 MFMA FRAGMENT layout
// ---------------------------------------------------------------------------
__global__ __launch_bounds__(256) void k_prepw(const float* __restrict__ W1,
                                               __bf16* __restrict__ f1h, __bf16* __restrict__ f1l,
                                               const float* __restrict__ W2,
                                               __bf16* __restrict__ f2h, __bf16* __restrict__ f2l) {
    int t = threadIdx.x + blockIdx.x * blockDim.x;   // 2048 threads
    for (int idx = t; idx < 16384; idx += 2048) {
        int j = idx & 7, lane = (idx >> 3) & 63, ch2 = (idx >> 9) & 7, c = idx >> 12;
        int k = ch2 * 32 + (lane >> 4) * 8 + j, col = c * 16 + (lane & 15);
        float w = W1[k * 64 + col];
        __bf16 h = (__bf16)w;
        f1h[idx] = h; f1l[idx] = (__bf16)(w - (float)h);
    }
    for (int idx = t; idx < 4096; idx += 2048) {
        int j = idx & 7, lane = (idx >> 3) & 63, ch2 = (idx >> 9) & 1, c = idx >> 10;
        int k = ch2 * 32 + (lane >> 4) * 8 + j, col = c * 16 + (lane & 15);
        float w = W2[k * 64 + col];
        __bf16 h = (__bf16)w;
        f2h[idx] = h; f2l[idx] = (__bf16)(w - (float)h);
    }
}

// ---------------------------------------------------------------------------
// GEMM1 (K=256, A fp32): LDS staging via global_load_lds(16B), double-buffered,
// seg-rotation swizzle. Output fp16, TRANSPOSED PLANES:
//   CT[c*N16 + r*16 + m], c = feature quarter (plane), N16 = nrows*16.
// ---------------------------------------------------------------------------
__global__ __launch_bounds__(256) void k_gemm1(const float* __restrict__ A,
                                               const __bf16* __restrict__ BfH,
                                               const __bf16* __restrict__ BfL,
                                               const float* __restrict__ dinv,
                                               _Float16* __restrict__ C, int nrows) {
    constexpr int K = 256, KC = 64, NCHK = 4, NCH32 = 8;
    __shared__ float As[2][64 * KC];       // 2 x 16 KB

    const int t = threadIdx.x;
    const int wave = t >> 6, lane = t & 63;
    const int m = lane & 15, q = lane >> 4;
    const int row0 = blockIdx.x * 64;
    const size_t N16 = (size_t)nrows * 16;

    const int s_sub = lane >> 4;
    const int s_seg = lane & 15;

    auto stage = [&](int ch, int buf) {
#pragma unroll
        for (int j = 0; j < 4; j++) {
            int lr = wave * 16 + j * 4 + s_sub;
            int gr = row0 + lr; if (gr > nrows - 1) gr = nrows - 1;
            int gs = (s_seg - lr) & 15;
            const float* g = A + (size_t)gr * K + ch * KC + gs * 4;
            float* l = &As[buf][(size_t)lr * KC + s_seg * 4];
            __builtin_amdgcn_global_load_lds(
                (const __attribute__((address_space(1))) void*)g,
                (__attribute__((address_space(3))) void*)l, 16, 0, 0);
        }
    };

    floatx4 acc[4] = {{0.f, 0.f, 0.f, 0.f}, {0.f, 0.f, 0.f, 0.f},
                      {0.f, 0.f, 0.f, 0.f}, {0.f, 0.f, 0.f, 0.f}};

    stage(0, 0);
    __syncthreads();

    for (int ch = 0; ch < NCHK; ch++) {
        if (ch + 1 < NCHK) stage(ch + 1, (ch + 1) & 1);

        const float* arow = &As[ch & 1][(size_t)(wave * 16 + m) * KC];
#pragma unroll
        for (int jj = 0; jj < 2; jj++) {
            int ch2 = ch * 2 + jj;
            int s0 = jj * 8 + q * 2;
            float4 v0 = *(const float4*)(arow + (((s0 + m) & 15) * 4));
            float4 v1 = *(const float4*)(arow + (((s0 + 1 + m) & 15) * 4));
            float af[8] = {v0.x, v0.y, v0.z, v0.w, v1.x, v1.y, v1.z, v1.w};
            bf16x8 ah, al;
#pragma unroll
            for (int j = 0; j < 8; j++) {
                __bf16 h = (__bf16)af[j];
                ah[j] = h;
                al[j] = (__bf16)(af[j] - (float)h);
            }
#pragma unroll
            for (int c = 0; c < 4; c++) {
                const bf16x8 bh = *(const bf16x8*)(BfH + ((size_t)(c * NCH32 + ch2) * 64 + lane) * 8);
                const bf16x8 bl = *(const bf16x8*)(BfL + ((size_t)(c * NCH32 + ch2) * 64 + lane) * 8);
                acc[c] = __builtin_amdgcn_mfma_f32_16x16x32_bf16(ah, bh, acc[c], 0, 0, 0);
                acc[c] = __builtin_amdgcn_mfma_f32_16x16x32_bf16(al, bh, acc[c], 0, 0, 0);
                acc[c] = __builtin_amdgcn_mfma_f32_16x16x32_bf16(ah, bl, acc[c], 0, 0, 0);
            }
        }
        __syncthreads();
    }

#pragma unroll
    for (int i = 0; i < 4; i++) {
        int r = row0 + wave * 16 + q * 4 + i;
        if (r < nrows) {
            float di = dinv[r];
#pragma unroll
            for (int c = 0; c < 4; c++)
                C[(size_t)c * N16 + (size_t)r * 16 + m] = (_Float16)(acc[c][i] * di);
        }
    }
}

// ---------------------------------------------------------------------------
// GEMM2 (K=64, A fp16 TRANSPOSED PLANES): single 8 KB LDS stage (LDS content
// identical to row-major version — only the global address computation maps
// segment gs -> plane (gs>>1), half (gs&1)). Output fp16 transposed planes.
// ---------------------------------------------------------------------------
__global__ __launch_bounds__(256) void k_gemm2(const _Float16* __restrict__ A,
                                               const __bf16* __restrict__ BfH,
                                               const __bf16* __restrict__ BfL,
                                               const float* __restrict__ dinv,
                                               _Float16* __restrict__ C, int nrows) {
    __shared__ _Float16 As[64 * 64];       // 8 KB
    const int t = threadIdx.x;
    const int wave = t >> 6, lane = t & 63;
    const int m = lane & 15, q = lane >> 4;
    const int row0 = blockIdx.x * 64;
    const size_t N16 = (size_t)nrows * 16;

#pragma unroll
    for (int j = 0; j < 2; j++) {
        int lr = j * 32 + wave * 8 + (lane >> 3);
        int p  = lane & 7;
        int gr = row0 + lr; if (gr > nrows - 1) gr = nrows - 1;
        int gs = (p - lr) & 7;                          // rotated seg
        const _Float16* g = A + (size_t)(gs >> 1) * N16 + (size_t)gr * 16 + (gs & 1) * 8;
        _Float16* l = &As[(size_t)lr * 64 + p * 8];
        __builtin_amdgcn_global_load_lds(
            (const __attribute__((address_space(1))) void*)g,
            (__attribute__((address_space(3))) void*)l, 16, 0, 0);
    }
    __syncthreads();

    floatx4 acc[4] = {{0.f, 0.f, 0.f, 0.f}, {0.f, 0.f, 0.f, 0.f},
                      {0.f, 0.f, 0.f, 0.f}, {0.f, 0.f, 0.f, 0.f}};

    const _Float16* arow = &As[(size_t)(wave * 16 + m) * 64];
#pragma unroll
    for (int jj = 0; jj < 2; jj++) {
        int s0 = jj * 4 + q;
        half8 v = *(const half8*)(arow + (((s0 + m) & 7) * 8));
        bf16x8 ah, al;
#pragma unroll
        for (int j = 0; j < 8; j++) {
            float f = (float)v[j];
            __bf16 h = (__bf16)f;
            ah[j] = h;
            al[j] = (__bf16)(f - (float)h);
        }
#pragma unroll
        for (int c = 0; c < 4; c++) {
            const bf16x8 bh = *(const bf16x8*)(BfH + ((size_t)(c * 2 + jj) * 64 + lane) * 8);
            const bf16x8 bl = *(const bf16x8*)(BfL + ((size_t)(c * 2 + jj) * 64 + lane) * 8);
            acc[c] = __builtin_amdgcn_mfma_f32_16x16x32_bf16(ah, bh, acc[c], 0, 0, 0);
            acc[c] = __builtin_amdgcn_mfma_f32_16x16x32_bf16(al, bh, acc[c], 0, 0, 0);
            acc[c] = __builtin_amdgcn_mfma_f32_16x16x32_bf16(ah, bl, acc[c], 0, 0, 0);
        }
    }

#pragma unroll
    for (int i = 0; i < 4; i++) {
        int r = row0 + wave * 16 + q * 4 + i;
        if (r < nrows) {
            float di = dinv[r];
#pragma unroll
            for (int c = 0; c < 4; c++)
                C[(size_t)c * N16 + (size_t)r * 16 + m] = (_Float16)(acc[c][i] * di);
        }
    }
}

// ---------------------------------------------------------------------------
// Edge-parallel aggregation over TRANSPOSED PLANES: 4 feature passes, each
// gathering from one 3.2 MB plane (L2-resident per XCD). Block = 64 nodes,
// 128 streams (2 lanes/edge, half8 = 16 B/lane, 32 edges/instr). Register
// run-accumulation (esrc dst-sorted), flush to LDS atomicAdd on row change.
// MODE 0: out planes = relu fp16   MODE 1: h3[d] = (relu @ W3)*dinv (fp32)
// ---------------------------------------------------------------------------
#define FLUSH() do {                                                          \
    float* ap = accph + cur * LDW;                                            \
    atomicAdd(ap + 0, a0); atomicAdd(ap + 1, a1);                             \
    atomicAdd(ap + 2, a2); atomicAdd(ap + 3, a3);                             \
    atomicAdd(ap + 4, a4); atomicAdd(ap + 5, a5);                             \
    atomicAdd(ap + 6, a6); atomicAdd(ap + 7, a7);                             \
} while (0)

#define STEPE(W, V, COND) do {                                                \
    if (COND) {                                                               \
        int row = (W) & 63;                                                   \
        float f0 = (float)(V)[0], f1 = (float)(V)[1];                         \
        float f2 = (float)(V)[2], f3 = (float)(V)[3];                         \
        float f4 = (float)(V)[4], f5 = (float)(V)[5];                         \
        float f6 = (float)(V)[6], f7 = (float)(V)[7];                         \
        if (row != cur) {                                                     \
            if (cur >= 0) FLUSH();                                            \
            cur = row;                                                        \
            a0 = f0; a1 = f1; a2 = f2; a3 = f3;                               \
            a4 = f4; a5 = f5; a6 = f6; a7 = f7;                               \
        } else {                                                              \
            a0 += f0; a1 += f1; a2 += f2; a3 += f3;                           \
            a4 += f4; a5 += f5; a6 += f6; a7 += f7;                           \
        }                                                                     \
    }                                                                         \
} while (0)

template <int MODE>
__global__ __launch_bounds__(256) void k_aggE(const _Float16* __restrict__ hs,
                                              const float* __restrict__ dinv,
                                              const int* __restrict__ rp,
                                              const int* __restrict__ esrc,
                                              const float* __restrict__ bias,
                                              const float* __restrict__ W3,
                                              void* __restrict__ out, int n) {
    constexpr int NPB = 64;          // nodes per block
    constexpr int LDW = 68;          // padded row stride (floats)
    __shared__ float acc[NPB * LDW]; // 17.4 KB

    const int t = threadIdx.x;
    const int wv = t >> 6, lane = t & 63;
    const int qe = lane >> 1;        // edge slot 0..31
    const int f8 = lane & 1;         // feature half-octet within the plane
    const int nb = blockIdx.x * NPB;
    const int ne = min(nb + NPB, n);
    const size_t N16 = (size_t)n * 16;

    for (int i = t; i < NPB * LDW; i += 256) acc[i] = 0.f;

    const int eb0 = rp[nb];
    const int eb1 = rp[ne];
    __syncthreads();

    // 128 contiguous streams: stream id = wave*32 + slot
    const int L   = eb1 - eb0;
    const int sl  = (L + 127) >> 7;
    const int sid = wv * 32 + qe;
    const int sa  = eb0 + sid * sl;
    const int sb  = min(sa + sl, eb1);

    if (sa < sb) {
        const int sbm1 = sb - 1;
        for (int ph = 0; ph < 4; ph++) {
            const _Float16* __restrict__ plane = hs + (size_t)ph * N16 + f8 * 8;
            float* __restrict__ accph = acc + ph * 16 + f8 * 8;
            int cur = -1;
            float a0 = 0.f, a1 = 0.f, a2 = 0.f, a3 = 0.f;
            float a4 = 0.f, a5 = 0.f, a6 = 0.f, a7 = 0.f;
            for (int e = sa; e < sb; e += 4) {
                int x1 = min(e + 1, sbm1);
                int x2 = min(e + 2, sbm1);
                int x3 = min(e + 3, sbm1);
                int w0 = esrc[e], w1 = esrc[x1], w2 = esrc[x2], w3 = esrc[x3];
                half8 v0 = *(const half8*)(plane + (size_t)(unsigned)(w0 >> 6) * 16);
                half8 v1 = *(const half8*)(plane + (size_t)(unsigned)(w1 >> 6) * 16);
                half8 v2 = *(const half8*)(plane + (size_t)(unsigned)(w2 >> 6) * 16);
                half8 v3 = *(const half8*)(plane + (size_t)(unsigned)(w3 >> 6) * 16);
                STEPE(w0, v0, true);
                STEPE(w1, v1, e + 1 < sb);
                STEPE(w2, v2, e + 2 < sb);
                STEPE(w3, v3, e + 3 < sb);
            }
            FLUSH();   // cur >= 0 guaranteed (sa < sb)
        }
    }
    __syncthreads();

    if (MODE == 0) {
        // thread t covers (node, plane): 64 nodes x 4 planes
        int nl = t >> 2, ph = t & 3;
        int node = nb + nl;
        if (node < n) {
            float dii = dinv[node];
            const float* ap = &acc[nl * LDW + ph * 16];
            const _Float16* sp = hs + (size_t)ph * N16 + (size_t)node * 16;
            _Float16* op = (_Float16*)out + (size_t)ph * N16 + (size_t)node * 16;
            const float4* bp = (const float4*)(bias + ph * 16);
            float4 b0 = bp[0], b1 = bp[1], b2 = bp[2], b3 = bp[3];
            float bb[16] = {b0.x, b0.y, b0.z, b0.w, b1.x, b1.y, b1.z, b1.w,
                            b2.x, b2.y, b2.z, b2.w, b3.x, b3.y, b3.z, b3.w};
            half8 s0 = *(const half8*)sp;
            half8 s1 = *(const half8*)(sp + 8);
            half8 o0, o1;
#pragma unroll
            for (int j = 0; j < 8; j++) {
                o0[j] = (_Float16)fmaxf((ap[j] + (float)s0[j]) * dii + bb[j], 0.f);
                o1[j] = (_Float16)fmaxf((ap[8 + j] + (float)s1[j]) * dii + bb[8 + j], 0.f);
            }
            *(half8*)op = o0;
            *(half8*)(op + 8) = o1;
        }
    } else {
#pragma unroll
        for (int it = 0; it < 16; it++) {
            int nl = it * 4 + wv;                      // one node per wave/iter
            int node = nb + nl;
            if (node < n) {
                float dii = dinv[node];
                float self = (float)hs[(size_t)(lane >> 4) * N16 + (size_t)node * 16 + (lane & 15)];
                float a = acc[nl * LDW + lane] + self;
                a = fmaxf(a * dii + bias[lane], 0.f);
                float2 w = ((const float2*)W3)[lane];
                float p0 = a * w.x, p1 = a * w.y;
#pragma unroll
                for (int o = 1; o <= 32; o <<= 1) {
                    p0 += __shfl_xor(p0, o, 64);
                    p1 += __shfl_xor(p1, o, 64);
                }
                if (lane == 0) ((float2*)out)[node] = make_float2(p0 * dii, p1 * dii);
            }
        }
    }
}

// ---------------------------------------------------------------------------
// Final layer: 2-wide aggregation + bias + log_softmax (thread per node)
// ---------------------------------------------------------------------------
__global__ __launch_bounds__(256) void k_final(const float2* __restrict__ h3s,
                                               const float* __restrict__ dinv,
                                               const int* __restrict__ rp,
                                               const int* __restrict__ esrc,
                                               const float* __restrict__ b3,
                                               float* __restrict__ out, int n) {
    int i = blockIdx.x * blockDim.x + threadIdx.x;
    if (i >= n) return;
    float dii = dinv[i];
    float2 h = h3s[i];
    float ax = h.x, ay = h.y;
    float bx = 0.f, by = 0.f, cx = 0.f, cy = 0.f, dx = 0.f, dy = 0.f;
    int e0 = rp[i], e1 = rp[i + 1];
    for (int e = e0; e < e1; e += 4) {
        int last = e1 - 1;
        int s0 = esrc[e] >> 6;
        int s1 = esrc[min(e + 1, last)] >> 6;
        int s2 = esrc[min(e + 2, last)] >> 6;
        int s3 = esrc[min(e + 3, last)] >> 6;
        float2 v0 = h3s[s0];
        float2 v1 = h3s[s1];
        float2 v2 = h3s[s2];
        float2 v3 = h3s[s3];
        ax += v0.x; ay += v0.y;
        bx += (e + 1 <= last) ? v1.x : 0.f; by += (e + 1 <= last) ? v1.y : 0.f;
        cx += (e + 2 <= last) ? v2.x : 0.f; cy += (e + 2 <= last) ? v2.y : 0.f;
        dx += (e + 3 <= last) ? v3.x : 0.f; dy += (e + 3 <= last) ? v3.y : 0.f;
    }
    float l0 = ((ax + bx) + (cx + dx)) * dii + b3[0];
    float l1 = ((ay + by) + (cy + dy)) * dii + b3[1];
    float mx = fmaxf(l0, l1);
    float lse = mx + log1pf(__expf(-fabsf(l0 - l1)));
    ((float2*)out)[i] = make_float2(l0 - lse, l1 - lse);
}

// ---------------------------------------------------------------------------
// Launch
// ---------------------------------------------------------------------------
extern "C" void kernel_launch(void* const* d_in, const int* in_sizes, int n_in,
                              void* d_out, int out_size, void* d_ws, size_t ws_size,
                              hipStream_t stream) {
    const float* x   = (const float*)d_in[0];
    const int*   ei  = (const int*)d_in[1];
    const float* W1  = (const float*)d_in[2];
    const float* b1  = (const float*)d_in[3];
    const float* W2  = (const float*)d_in[4];
    const float* b2  = (const float*)d_in[5];
    const float* W3  = (const float*)d_in[6];
    const float* b3  = (const float*)d_in[7];
    float* out = (float*)d_out;

    const int N = in_sizes[0] / F_IN;   // 100000
    const int E = in_sizes[1] / 2;      // 1600000
    const int* src = ei;
    const int* dst = ei + E;

    const int NBK = (N + BSPAN - 1) / BSPAN;      // 391
    const int NCH = (E + CHUNK - 1) / CHUNK;      // 391
    const int S   = NBK * NCH;

    // workspace bump allocator (256B aligned)
    char* p = (char*)d_ws;
    auto alloc = [&](size_t bytes) -> void* {
        void* r = (void*)p;
        p += (bytes + 255) & ~(size_t)255;
        return r;
    };
    int*      cntT     = (int*)alloc((size_t)S * 4);
    int*      off      = (int*)alloc((size_t)(S + 1) * 4);
    int*      partials = (int*)alloc(4096);
    int*      ebuf     = (int*)alloc((size_t)E * 4);
    int*      esrc     = (int*)alloc((size_t)(E + 64) * 4);   // +pad
    int*      rp       = (int*)alloc((size_t)(N + 1) * 4);
    float*    dinv     = (float*)alloc((size_t)N * 4);
    _Float16* bufA     = (_Float16*)alloc((size_t)N * HID * 2);  // 4 planes of N*16
    _Float16* bufB     = (_Float16*)alloc((size_t)N * HID * 2);  // 4 planes of N*16
    float*    h3       = (float*)alloc((size_t)N * 2 * 4);
    __bf16*   f1h      = (__bf16*)alloc(16384 * 2);
    __bf16*   f1l      = (__bf16*)alloc(16384 * 2);
    __bf16*   f2h      = (__bf16*)alloc(4096 * 2);
    __bf16*   f2l      = (__bf16*)alloc(4096 * 2);

    const int T = 256;
    int scanBlocks = (S + 1023) / 1024;

    // weight prep (independent of CSR chain)
    k_prepw<<<8, T, 0, stream>>>(W1, f1h, f1l, W2, f2h, f2l);

    // CSR build via locality-aware counting sort
    k_hist<<<NCH, T, 0, stream>>>(dst, cntT, E, NCH, NBK);
    k_scanA<<<scanBlocks, T, 0, stream>>>(cntT, off, partials, S);
    k_scanB<<<1, 64, 0, stream>>>(partials, off, scanBlocks, S);
    k_scanC<<<(S + T - 1) / T, T, 0, stream>>>(off, partials, S);
    k_sortwrite<<<NCH, T, 0, stream>>>(src, dst, off, ebuf, E, NCH, NBK);
    k_bucket_csr<<<NBK, T, 0, stream>>>(off, ebuf, rp, dinv, esrc, N, NCH, NBK);

    // layer 1
    int gemmBlocks = (N + 63) / 64;
    int aggBlocks  = (N + 63) / 64;
    k_gemm1<<<gemmBlocks, T, 0, stream>>>(x, f1h, f1l, dinv, bufA, N);
    k_aggE<0><<<aggBlocks, T, 0, stream>>>(bufA, dinv, rp, esrc, b1, nullptr, bufB, N);

    // layer 2 (+ fused GEMM3)
    k_gemm2<<<gemmBlocks, T, 0, stream>>>(bufB, f2h, f2l, dinv, bufA, N);
    k_aggE<1><<<aggBlocks, T, 0, stream>>>(bufA, dinv, rp, esrc, b2, W3, h3, N);

    // layer 3 + log_softmax
    k_final<<<(N + T - 1) / T, T, 0, stream>>>((const float2*)h3, dinv, rp, esrc, b3, out, N);
}

// Round 7
// 451.757 us; speedup vs baseline: 1.1505x; 1.1505x over previous
//
#include <hip/hip_runtime.h>
#include <math.h>

#define F_IN 256
#define HID  64
#define BSH  8              // bucket = dst >> 8 (256 nodes per bucket)
#define BSPAN 256
#define CHUNK 4096          // edges per sort block (16 per thread)
#define NBK_MAX 512

typedef __bf16   bf16x8 __attribute__((ext_vector_type(8)));
typedef float    floatx4 __attribute__((ext_vector_type(4)));
typedef _Float16 half4v __attribute__((ext_vector_type(4)));

// ---------------------------------------------------------------------------
// Fused pass: per-chunk histogram over coarse dst buckets + (blocks 0..7)
// weight prep W[K x 64] -> split-bf16 MFMA fragment layout.
// ---------------------------------------------------------------------------
__global__ __launch_bounds__(256) void k_pre(const int* __restrict__ dst,
                                             int* __restrict__ cntT,
                                             int E, int NCH, int NBK,
                                             const float* __restrict__ W1,
                                             __bf16* __restrict__ f1h, __bf16* __restrict__ f1l,
                                             const float* __restrict__ W2,
                                             __bf16* __restrict__ f2h, __bf16* __restrict__ f2l) {
    __shared__ int hist[NBK_MAX];
    int t = threadIdx.x, c = blockIdx.x;
    hist[t] = 0; hist[t + 256] = 0;
    __syncthreads();
    int base = c * CHUNK;
#pragma unroll 4
    for (int j = 0; j < CHUNK / 256; j++) {
        int e = base + j * 256 + t;
        if (e < E) atomicAdd(&hist[dst[e] >> BSH], 1);
    }
    __syncthreads();
    for (int b = t; b < NBK; b += 256) cntT[b * NCH + c] = hist[b];

    if (c < 8) {
        int g = c * 256 + t;                      // 0..2047
        for (int idx = g; idx < 16384; idx += 2048) {
            int j = idx & 7, lane = (idx >> 3) & 63, ch2 = (idx >> 9) & 7, cc = idx >> 12;
            int k = ch2 * 32 + (lane >> 4) * 8 + j, col = cc * 16 + (lane & 15);
            float w = W1[k * 64 + col];
            __bf16 h = (__bf16)w;
            f1h[idx] = h; f1l[idx] = (__bf16)(w - (float)h);
        }
        for (int idx = g; idx < 4096; idx += 2048) {
            int j = idx & 7, lane = (idx >> 3) & 63, ch2 = (idx >> 9) & 1, cc = idx >> 10;
            int k = ch2 * 32 + (lane >> 4) * 8 + j, col = cc * 16 + (lane & 15);
            float w = W2[k * 64 + col];
            __bf16 h = (__bf16)w;
            f2h[idx] = h; f2l[idx] = (__bf16)(w - (float)h);
        }
    }
}

// ---------------------------------------------------------------------------
// Exclusive scan of cntT (S elements) -> off, plus sentinel off[S] = total
// ---------------------------------------------------------------------------
__global__ __launch_bounds__(256) void k_scanA(const int* __restrict__ cntT,
                                               int* __restrict__ off,
                                               int* __restrict__ partials, int S) {
    __shared__ int sh[256];
    int tid = threadIdx.x;
    int base = blockIdx.x * 1024 + tid * 4;
    int v[4];
    int s = 0;
#pragma unroll
    for (int j = 0; j < 4; j++) {
        int idx = base + j;
        v[j] = (idx < S) ? cntT[idx] : 0;
        s += v[j];
    }
    sh[tid] = s;
    __syncthreads();
    int mysum = s;
    for (int o = 1; o < 256; o <<= 1) {
        int tv = (tid >= o) ? sh[tid - o] : 0;
        __syncthreads();
        sh[tid] += tv;
        __syncthreads();
    }
    int pref = sh[tid] - mysum;
#pragma unroll
    for (int j = 0; j < 4; j++) {
        int idx = base + j;
        if (idx < S) off[idx] = pref;
        pref += v[j];
    }
    if (tid == 255) partials[blockIdx.x] = sh[255];
}

__global__ void k_scanB(int* __restrict__ partials, int* __restrict__ off,
                        int nblk, int S) {
    if (blockIdx.x == 0 && threadIdx.x == 0) {
        int run = 0;
        for (int b = 0; b < nblk; b++) { int t = partials[b]; partials[b] = run; run += t; }
        off[S] = run;   // == E
    }
}

__global__ void k_scanC(int* __restrict__ off, const int* __restrict__ partials, int S) {
    int i = blockIdx.x * blockDim.x + threadIdx.x;
    if (i < S) off[i] += partials[i >> 10];
}

// ---------------------------------------------------------------------------
// Pass 2: scatter edges into bucket-grouped ebuf. Entry = (src<<8)|(dst&255)
// ---------------------------------------------------------------------------
__global__ __launch_bounds__(256) void k_sortwrite(const int* __restrict__ src,
                                                   const int* __restrict__ dst,
                                                   const int* __restrict__ off,
                                                   int* __restrict__ ebuf,
                                                   int E, int NCH, int NBK) {
    __shared__ int cur[NBK_MAX];
    int t = threadIdx.x, c = blockIdx.x;
    for (int b = t; b < NBK; b += 256) cur[b] = off[b * NCH + c];
    __syncthreads();
    int base = c * CHUNK;
#pragma unroll 4
    for (int j = 0; j < CHUNK / 256; j++) {
        int e = base + j * 256 + t;
        if (e < E) {
            int s = src[e];
            int d = dst[e];
            int pos = atomicAdd(&cur[d >> BSH], 1);
            ebuf[pos] = (s << BSH) | (d & (BSPAN - 1));
        }
    }
}

// ---------------------------------------------------------------------------
// Pass 3: per-bucket node-level CSR: rp, dinv, node-sorted esrc (plain src)
// ---------------------------------------------------------------------------
__global__ __launch_bounds__(256) void k_bucket_csr(const int* __restrict__ off,
                                                    const int* __restrict__ ebuf,
                                                    int* __restrict__ rp,
                                                    float* __restrict__ dinv,
                                                    int* __restrict__ esrc,
                                                    int N, int NCH, int NBK) {
    __shared__ int cnt[BSPAN];
    __shared__ int sh[BSPAN];
    int b = blockIdx.x, t = threadIdx.x;
    int base = off[b * NCH];
    int end  = off[(b + 1) * NCH];

    cnt[t] = 0;
    __syncthreads();
    for (int i = base + t; i < end; i += 256) atomicAdd(&cnt[ebuf[i] & (BSPAN - 1)], 1);
    __syncthreads();

    int c = cnt[t];
    sh[t] = c;
    __syncthreads();
    for (int o = 1; o < 256; o <<= 1) {
        int tv = (t >= o) ? sh[t - o] : 0;
        __syncthreads();
        sh[t] += tv;
        __syncthreads();
    }
    int excl = sh[t] - c;

    int node = (b << BSH) + t;
    if (node < N) {
        rp[node] = base + excl;
        dinv[node] = rsqrtf((float)(1 + c));
    }
    if (b == NBK - 1) {
        if (t == 0) rp[N] = end;
        if (t < 16) esrc[end + t] = 0;     // pad (loads are clamped anyway)
    }
    __syncthreads();

    cnt[t] = base + excl;
    __syncthreads();
    for (int i = base + t; i < end; i += 256) {
        int v = ebuf[i];
        int p = atomicAdd(&cnt[v & (BSPAN - 1)], 1);
        esrc[p] = v >> BSH;                // plain src index
    }
}

// ---------------------------------------------------------------------------
// GEMM1 (K=256, A fp32): LDS staging via global_load_lds(16B), double-buffered,
// seg-rotation swizzle. Output fp16 (scaled by dinv[row]).
// ---------------------------------------------------------------------------
__global__ __launch_bounds__(256) void k_gemm1(const float* __restrict__ A,
                                               const __bf16* __restrict__ BfH,
                                               const __bf16* __restrict__ BfL,
                                               const float* __restrict__ dinv,
                                               _Float16* __restrict__ C, int nrows) {
    constexpr int K = 256, KC = 64, NCHK = 4, NCH32 = 8;
    __shared__ float As[2][64 * KC];       // 2 x 16 KB

    const int t = threadIdx.x;
    const int wave = t >> 6, lane = t & 63;
    const int m = lane & 15, q = lane >> 4;
    const int row0 = blockIdx.x * 64;

    const int s_sub = lane >> 4;
    const int s_seg = lane & 15;

    auto stage = [&](int ch, int buf) {
#pragma unroll
        for (int j = 0; j < 4; j++) {
            int lr = wave * 16 + j * 4 + s_sub;
            int gr = row0 + lr; if (gr > nrows - 1) gr = nrows - 1;
            int gs = (s_seg - lr) & 15;
            const float* g = A + (size_t)gr * K + ch * KC + gs * 4;
            float* l = &As[buf][(size_t)lr * KC + s_seg * 4];
            __builtin_amdgcn_global_load_lds(
                (const __attribute__((address_space(1))) void*)g,
                (__attribute__((address_space(3))) void*)l, 16, 0, 0);
        }
    };

    floatx4 acc[4] = {{0.f, 0.f, 0.f, 0.f}, {0.f, 0.f, 0.f, 0.f},
                      {0.f, 0.f, 0.f, 0.f}, {0.f, 0.f, 0.f, 0.f}};

    stage(0, 0);
    __syncthreads();

    for (int ch = 0; ch < NCHK; ch++) {
        if (ch + 1 < NCHK) stage(ch + 1, (ch + 1) & 1);

        const float* arow = &As[ch & 1][(size_t)(wave * 16 + m) * KC];
#pragma unroll
        for (int jj = 0; jj < 2; jj++) {
            int ch2 = ch * 2 + jj;
            int s0 = jj * 8 + q * 2;
            float4 v0 = *(const float4*)(arow + (((s0 + m) & 15) * 4));
            float4 v1 = *(const float4*)(arow + (((s0 + 1 + m) & 15) * 4));
            float af[8] = {v0.x, v0.y, v0.z, v0.w, v1.x, v1.y, v1.z, v1.w};
            bf16x8 ah, al;
#pragma unroll
            for (int j = 0; j < 8; j++) {
                __bf16 h = (__bf16)af[j];
                ah[j] = h;
                al[j] = (__bf16)(af[j] - (float)h);
            }
#pragma unroll
            for (int c = 0; c < 4; c++) {
                const bf16x8 bh = *(const bf16x8*)(BfH + ((size_t)(c * NCH32 + ch2) * 64 + lane) * 8);
                const bf16x8 bl = *(const bf16x8*)(BfL + ((size_t)(c * NCH32 + ch2) * 64 + lane) * 8);
                acc[c] = __builtin_amdgcn_mfma_f32_16x16x32_bf16(ah, bh, acc[c], 0, 0, 0);
                acc[c] = __builtin_amdgcn_mfma_f32_16x16x32_bf16(al, bh, acc[c], 0, 0, 0);
                acc[c] = __builtin_amdgcn_mfma_f32_16x16x32_bf16(ah, bl, acc[c], 0, 0, 0);
            }
        }
        __syncthreads();
    }

#pragma unroll
    for (int i = 0; i < 4; i++) {
        int r = row0 + wave * 16 + q * 4 + i;
        if (r < nrows) {
            float di = dinv[r];
#pragma unroll
            for (int c = 0; c < 4; c++)
                C[(size_t)r * 64 + c * 16 + m] = (_Float16)(acc[c][i] * di);
        }
    }
}

// ---------------------------------------------------------------------------
// Fused layer-1 aggregation + GEMM2.
// Phase 1 (round-1 per-node agg): block = 64 nodes, each wave processes 16
// nodes sequentially; relu'd rows land in a 64x68 fp32 LDS tile.
// Phase 2: 64x64x64 split-bf16 MFMA with W2 fragments -> h2 = (tile@W2)*dinv
// written fp16 (identical math/fragment mapping to the former k_gemm2).
// ---------------------------------------------------------------------------
__global__ __launch_bounds__(256) void k_aggG(const _Float16* __restrict__ hs,
                                              const float* __restrict__ dinv,
                                              const int* __restrict__ rp,
                                              const int* __restrict__ esrc,
                                              const float* __restrict__ bias,
                                              const __bf16* __restrict__ BfH,
                                              const __bf16* __restrict__ BfL,
                                              _Float16* __restrict__ C, int n) {
    constexpr int LDW = 68;            // padded row stride (floats)
    __shared__ float As[64 * LDW];     // 17.4 KB

    const int t = threadIdx.x;
    const int wave = t >> 6, lane = t & 63;
    const int qe = lane >> 4, fg = lane & 15;
    const int row0 = blockIdx.x * 64;

    // ---- phase 1: per-node aggregation, 16 nodes per wave
    for (int i = 0; i < 16; i++) {
        int row = wave * 16 + i;
        int nid = row0 + row;
        if (nid < n) {
            float dii = dinv[nid];
            int e0 = rp[nid];
            int e1 = rp[nid + 1];
            int last = e1 - 1;

            float a0 = 0.f, a1 = 0.f, a2 = 0.f, a3 = 0.f;
            if (qe == 0) {
                half4v sv = *(const half4v*)(hs + (size_t)nid * 64 + fg * 4);
                a0 = (float)sv[0]; a1 = (float)sv[1]; a2 = (float)sv[2]; a3 = (float)sv[3];
            }
            for (int e = e0; e <= last; e += 16) {
#pragma unroll
                for (int u = 0; u < 4; u++) {
                    int slot = e + u * 4 + qe;
                    int idx = esrc[min(slot, last)];
                    half4v v = *(const half4v*)(hs + (size_t)idx * 64 + fg * 4);
                    if (slot <= last) {
                        a0 += (float)v[0]; a1 += (float)v[1];
                        a2 += (float)v[2]; a3 += (float)v[3];
                    }
                }
            }
#pragma unroll
            for (int o = 16; o <= 32; o <<= 1) {
                a0 += __shfl_xor(a0, o, 64);
                a1 += __shfl_xor(a1, o, 64);
                a2 += __shfl_xor(a2, o, 64);
                a3 += __shfl_xor(a3, o, 64);
            }
            if (qe == 0) {
                float4 b4 = ((const float4*)bias)[fg];
                float* r = &As[row * LDW + fg * 4];
                r[0] = fmaxf(a0 * dii + b4.x, 0.f);
                r[1] = fmaxf(a1 * dii + b4.y, 0.f);
                r[2] = fmaxf(a2 * dii + b4.z, 0.f);
                r[3] = fmaxf(a3 * dii + b4.w, 0.f);
            }
        } else if (qe == 0) {
            float* r = &As[row * LDW + fg * 4];
            r[0] = 0.f; r[1] = 0.f; r[2] = 0.f; r[3] = 0.f;
        }
    }
    __syncthreads();

    // ---- phase 2: 64x64x64 GEMM vs W2 (split-bf16), rows from LDS fp32
    const int m = lane & 15, q = lane >> 4;
    floatx4 acc[4] = {{0.f, 0.f, 0.f, 0.f}, {0.f, 0.f, 0.f, 0.f},
                      {0.f, 0.f, 0.f, 0.f}, {0.f, 0.f, 0.f, 0.f}};

    const float* arow = &As[(size_t)(wave * 16 + m) * LDW];
#pragma unroll
    for (int jj = 0; jj < 2; jj++) {
        // lane's 8 k-values: k = jj*32 + q*8 + 0..7 (matches f2 fragment prep)
        float4 v0 = *(const float4*)(arow + jj * 32 + q * 8);
        float4 v1 = *(const float4*)(arow + jj * 32 + q * 8 + 4);
        float af[8] = {v0.x, v0.y, v0.z, v0.w, v1.x, v1.y, v1.z, v1.w};
        bf16x8 ah, al;
#pragma unroll
        for (int j = 0; j < 8; j++) {
            __bf16 h = (__bf16)af[j];
            ah[j] = h;
            al[j] = (__bf16)(af[j] - (float)h);
        }
#pragma unroll
        for (int c = 0; c < 4; c++) {
            const bf16x8 bh = *(const bf16x8*)(BfH + ((size_t)(c * 2 + jj) * 64 + lane) * 8);
            const bf16x8 bl = *(const bf16x8*)(BfL + ((size_t)(c * 2 + jj) * 64 + lane) * 8);
            acc[c] = __builtin_amdgcn_mfma_f32_16x16x32_bf16(ah, bh, acc[c], 0, 0, 0);
            acc[c] = __builtin_amdgcn_mfma_f32_16x16x32_bf16(al, bh, acc[c], 0, 0, 0);
            acc[c] = __builtin_amdgcn_mfma_f32_16x16x32_bf16(ah, bl, acc[c], 0, 0, 0);
        }
    }

#pragma unroll
    for (int i = 0; i < 4; i++) {
        int r = row0 + wave * 16 + q * 4 + i;
        if (r < n) {
            float di = dinv[r];
#pragma unroll
            for (int c = 0; c < 4; c++)
                C[(size_t)r * 64 + c * 16 + m] = (_Float16)(acc[c][i] * di);
        }
    }
}

// ---------------------------------------------------------------------------
// Layer-2 aggregation + fused W3: one wave per node (round-1 structure).
// h3[d] = (relu(dinv*(h2[d]+sum h2[src])+b2) @ W3) * dinv[d]   (fp32 x2)
// ---------------------------------------------------------------------------
__global__ __launch_bounds__(256) void k_agg3(const _Float16* __restrict__ hs,
                                              const float* __restrict__ dinv,
                                              const int* __restrict__ rp,
                                              const int* __restrict__ esrc,
                                              const float* __restrict__ bias,
                                              const float* __restrict__ W3,
                                              float2* __restrict__ out, int n) {
    int lane = threadIdx.x & 63;
    int qe = lane >> 4;
    int fg = lane & 15;
    int nid = blockIdx.x * 4 + (threadIdx.x >> 6);
    if (nid >= n) return;
    nid = __builtin_amdgcn_readfirstlane(nid);

    float dii = dinv[nid];
    int e0 = rp[nid];
    int e1 = rp[nid + 1];
    int last = e1 - 1;

    float a0 = 0.f, a1 = 0.f, a2 = 0.f, a3 = 0.f;
    if (qe == 0) {
        half4v sv = *(const half4v*)(hs + (size_t)nid * 64 + fg * 4);
        a0 = (float)sv[0]; a1 = (float)sv[1]; a2 = (float)sv[2]; a3 = (float)sv[3];
    }

    for (int e = e0; e <= last; e += 16) {
#pragma unroll
        for (int u = 0; u < 4; u++) {
            int slot = e + u * 4 + qe;
            int idx = esrc[min(slot, last)];
            half4v v = *(const half4v*)(hs + (size_t)idx * 64 + fg * 4);
            if (slot <= last) {
                a0 += (float)v[0]; a1 += (float)v[1];
                a2 += (float)v[2]; a3 += (float)v[3];
            }
        }
    }

#pragma unroll
    for (int o = 16; o <= 32; o <<= 1) {
        a0 += __shfl_xor(a0, o, 64);
        a1 += __shfl_xor(a1, o, 64);
        a2 += __shfl_xor(a2, o, 64);
        a3 += __shfl_xor(a3, o, 64);
    }

    float4 b4 = ((const float4*)bias)[fg];
    a0 = fmaxf(a0 * dii + b4.x, 0.f);
    a1 = fmaxf(a1 * dii + b4.y, 0.f);
    a2 = fmaxf(a2 * dii + b4.z, 0.f);
    a3 = fmaxf(a3 * dii + b4.w, 0.f);

    const float2* w3 = (const float2*)W3;
    float2 w0 = w3[fg * 4 + 0], w1 = w3[fg * 4 + 1];
    float2 w2 = w3[fg * 4 + 2], w3v = w3[fg * 4 + 3];
    float p0 = a0 * w0.x + a1 * w1.x + a2 * w2.x + a3 * w3v.x;
    float p1 = a0 * w0.y + a1 * w1.y + a2 * w2.y + a3 * w3v.y;
#pragma unroll
    for (int o = 1; o <= 8; o <<= 1) {
        p0 += __shfl_xor(p0, o, 64);
        p1 += __shfl_xor(p1, o, 64);
    }
    if (lane == 0) out[nid] = make_float2(p0 * dii, p1 * dii);
}

// ---------------------------------------------------------------------------
// Final layer: 2-wide aggregation + bias + log_softmax (thread per node)
// ---------------------------------------------------------------------------
__global__ __launch_bounds__(256) void k_final(const float2* __restrict__ h3s,
                                               const float* __restrict__ dinv,
                                               const int* __restrict__ rp,
                                               const int* __restrict__ esrc,
                                               const float* __restrict__ b3,
                                               float* __restrict__ out, int n) {
    int i = blockIdx.x * blockDim.x + threadIdx.x;
    if (i >= n) return;
    float dii = dinv[i];
    float2 h = h3s[i];
    float ax = h.x, ay = h.y;
    float bx = 0.f, by = 0.f, cx = 0.f, cy = 0.f, dx = 0.f, dy = 0.f;
    int e0 = rp[i], e1 = rp[i + 1];
    for (int e = e0; e < e1; e += 4) {
        int last = e1 - 1;
        int s0 = esrc[e];
        int s1 = esrc[min(e + 1, last)];
        int s2 = esrc[min(e + 2, last)];
        int s3 = esrc[min(e + 3, last)];
        float2 v0 = h3s[s0];
        float2 v1 = h3s[s1];
        float2 v2 = h3s[s2];
        float2 v3 = h3s[s3];
        ax += v0.x; ay += v0.y;
        bx += (e + 1 <= last) ? v1.x : 0.f; by += (e + 1 <= last) ? v1.y : 0.f;
        cx += (e + 2 <= last) ? v2.x : 0.f; cy += (e + 2 <= last) ? v2.y : 0.f;
        dx += (e + 3 <= last) ? v3.x : 0.f; dy += (e + 3 <= last) ? v3.y : 0.f;
    }
    float l0 = ((ax + bx) + (cx + dx)) * dii + b3[0];
    float l1 = ((ay + by) + (cy + dy)) * dii + b3[1];
    float mx = fmaxf(l0, l1);
    float lse = mx + log1pf(__expf(-fabsf(l0 - l1)));
    ((float2*)out)[i] = make_float2(l0 - lse, l1 - lse);
}

// ---------------------------------------------------------------------------
// Launch
// ---------------------------------------------------------------------------
extern "C" void kernel_launch(void* const* d_in, const int* in_sizes, int n_in,
                              void* d_out, int out_size, void* d_ws, size_t ws_size,
                              hipStream_t stream) {
    const float* x   = (const float*)d_in[0];
    const int*   ei  = (const int*)d_in[1];
    const float* W1  = (const float*)d_in[2];
    const float* b1  = (const float*)d_in[3];
    const float* W2  = (const float*)d_in[4];
    const float* b2  = (const float*)d_in[5];
    const float* W3  = (const float*)d_in[6];
    const float* b3  = (const float*)d_in[7];
    float* out = (float*)d_out;

    const int N = in_sizes[0] / F_IN;   // 100000
    const int E = in_sizes[1] / 2;      // 1600000
    const int* src = ei;
    const int* dst = ei + E;

    const int NBK = (N + BSPAN - 1) / BSPAN;      // 391
    const int NCH = (E + CHUNK - 1) / CHUNK;      // 391
    const int S   = NBK * NCH;

    // workspace bump allocator (256B aligned)
    char* p = (char*)d_ws;
    auto alloc = [&](size_t bytes) -> void* {
        void* r = (void*)p;
        p += (bytes + 255) & ~(size_t)255;
        return r;
    };
    int*      cntT     = (int*)alloc((size_t)S * 4);
    int*      off      = (int*)alloc((size_t)(S + 1) * 4);
    int*      partials = (int*)alloc(4096);
    int*      ebuf     = (int*)alloc((size_t)E * 4);
    int*      esrc     = (int*)alloc((size_t)(E + 64) * 4);   // +pad
    int*      rp       = (int*)alloc((size_t)(N + 1) * 4);
    float*    dinv     = (float*)alloc((size_t)N * 4);
    _Float16* bufA     = (_Float16*)alloc((size_t)N * HID * 2);  // h1
    _Float16* bufB     = (_Float16*)alloc((size_t)N * HID * 2);  // h2
    float*    h3       = (float*)alloc((size_t)N * 2 * 4);
    __bf16*   f1h      = (__bf16*)alloc(16384 * 2);
    __bf16*   f1l      = (__bf16*)alloc(16384 * 2);
    __bf16*   f2h      = (__bf16*)alloc(4096 * 2);
    __bf16*   f2l      = (__bf16*)alloc(4096 * 2);

    const int T = 256;
    int scanBlocks = (S + 1023) / 1024;

    // CSR build (hist fused with weight prep) via locality-aware counting sort
    k_pre<<<NCH, T, 0, stream>>>(dst, cntT, E, NCH, NBK, W1, f1h, f1l, W2, f2h, f2l);
    k_scanA<<<scanBlocks, T, 0, stream>>>(cntT, off, partials, S);
    k_scanB<<<1, 64, 0, stream>>>(partials, off, scanBlocks, S);
    k_scanC<<<(S + T - 1) / T, T, 0, stream>>>(off, partials, S);
    k_sortwrite<<<NCH, T, 0, stream>>>(src, dst, off, ebuf, E, NCH, NBK);
    k_bucket_csr<<<NBK, T, 0, stream>>>(off, ebuf, rp, dinv, esrc, N, NCH, NBK);

    // layer 1 GEMM
    int gemmBlocks = (N + 63) / 64;
    k_gemm1<<<gemmBlocks, T, 0, stream>>>(x, f1h, f1l, dinv, bufA, N);

    // layer-1 agg + fused GEMM2
    k_aggG<<<gemmBlocks, T, 0, stream>>>(bufA, dinv, rp, esrc, b1, f2h, f2l, bufB, N);

    // layer-2 agg + fused GEMM3
    k_agg3<<<(N + 3) / 4, T, 0, stream>>>(bufB, dinv, rp, esrc, b2, W3, (float2*)h3, N);

    // layer 3 + log_softmax
    k_final<<<(N + T - 1) / T, T, 0, stream>>>((const float2*)h3, dinv, rp, esrc, b3, out, N);
}

// Round 8
// 402.775 us; speedup vs baseline: 1.2904x; 1.1216x over previous
//
#include <hip/hip_runtime.h>
#include <math.h>

#define F_IN 256
#define HID  64
#define BSH  8              // bucket = dst >> 8 (256 nodes per bucket)
#define BSPAN 256
#define CHUNK 4096          // edges per sort block (16 per thread)
#define NBK_MAX 512

typedef __bf16   bf16x8 __attribute__((ext_vector_type(8)));
typedef float    floatx4 __attribute__((ext_vector_type(4)));
typedef _Float16 half8 __attribute__((ext_vector_type(8)));
typedef _Float16 half4v __attribute__((ext_vector_type(4)));

// ---------------------------------------------------------------------------
// Fused pass: per-chunk histogram over coarse dst buckets + (blocks 0..7)
// weight prep W[K x 64] -> split-bf16 MFMA fragment layout.
// ---------------------------------------------------------------------------
__global__ __launch_bounds__(256) void k_pre(const int* __restrict__ dst,
                                             int* __restrict__ cntT,
                                             int E, int NCH, int NBK,
                                             const float* __restrict__ W1,
                                             __bf16* __restrict__ f1h, __bf16* __restrict__ f1l,
                                             const float* __restrict__ W2,
                                             __bf16* __restrict__ f2h, __bf16* __restrict__ f2l) {
    __shared__ int hist[NBK_MAX];
    int t = threadIdx.x, c = blockIdx.x;
    hist[t] = 0; hist[t + 256] = 0;
    __syncthreads();
    int base = c * CHUNK;
#pragma unroll 4
    for (int j = 0; j < CHUNK / 256; j++) {
        int e = base + j * 256 + t;
        if (e < E) atomicAdd(&hist[dst[e] >> BSH], 1);
    }
    __syncthreads();
    for (int b = t; b < NBK; b += 256) cntT[b * NCH + c] = hist[b];

    if (c < 8) {
        int g = c * 256 + t;                      // 0..2047
        for (int idx = g; idx < 16384; idx += 2048) {
            int j = idx & 7, lane = (idx >> 3) & 63, ch2 = (idx >> 9) & 7, cc = idx >> 12;
            int k = ch2 * 32 + (lane >> 4) * 8 + j, col = cc * 16 + (lane & 15);
            float w = W1[k * 64 + col];
            __bf16 h = (__bf16)w;
            f1h[idx] = h; f1l[idx] = (__bf16)(w - (float)h);
        }
        for (int idx = g; idx < 4096; idx += 2048) {
            int j = idx & 7, lane = (idx >> 3) & 63, ch2 = (idx >> 9) & 1, cc = idx >> 10;
            int k = ch2 * 32 + (lane >> 4) * 8 + j, col = cc * 16 + (lane & 15);
            float w = W2[k * 64 + col];
            __bf16 h = (__bf16)w;
            f2h[idx] = h; f2l[idx] = (__bf16)(w - (float)h);
        }
    }
}

// ---------------------------------------------------------------------------
// Exclusive scan of cntT (S elements) -> off (block-local) + partials
// ---------------------------------------------------------------------------
__global__ __launch_bounds__(256) void k_scanA(const int* __restrict__ cntT,
                                               int* __restrict__ off,
                                               int* __restrict__ partials, int S) {
    __shared__ int sh[256];
    int tid = threadIdx.x;
    int base = blockIdx.x * 1024 + tid * 4;
    int v[4];
    int s = 0;
#pragma unroll
    for (int j = 0; j < 4; j++) {
        int idx = base + j;
        v[j] = (idx < S) ? cntT[idx] : 0;
        s += v[j];
    }
    sh[tid] = s;
    __syncthreads();
    int mysum = s;
    for (int o = 1; o < 256; o <<= 1) {
        int tv = (tid >= o) ? sh[tid - o] : 0;
        __syncthreads();
        sh[tid] += tv;
        __syncthreads();
    }
    int pref = sh[tid] - mysum;
#pragma unroll
    for (int j = 0; j < 4; j++) {
        int idx = base + j;
        if (idx < S) off[idx] = pref;
        pref += v[j];
    }
    if (tid == 255) partials[blockIdx.x] = sh[255];
}

__global__ void k_scanB(int* __restrict__ partials, int* __restrict__ off,
                        int nblk, int S) {
    if (blockIdx.x == 0 && threadIdx.x == 0) {
        int run = 0;
        for (int b = 0; b < nblk; b++) { int t = partials[b]; partials[b] = run; run += t; }
        off[S] = run;   // == E (absolute sentinel)
    }
}

// ---------------------------------------------------------------------------
// Pass 2: scatter edges into bucket-grouped ebuf. Entry = (src<<8)|(dst&255)
// (partial-add folded in: off[] is block-local, + partials[idx>>10])
// ---------------------------------------------------------------------------
__global__ __launch_bounds__(256) void k_sortwrite(const int* __restrict__ src,
                                                   const int* __restrict__ dst,
                                                   const int* __restrict__ off,
                                                   const int* __restrict__ partials,
                                                   int* __restrict__ ebuf,
                                                   int E, int NCH, int NBK) {
    __shared__ int cur[NBK_MAX];
    int t = threadIdx.x, c = blockIdx.x;
    for (int b = t; b < NBK; b += 256) {
        int idx = b * NCH + c;
        cur[b] = off[idx] + partials[idx >> 10];
    }
    __syncthreads();
    int base = c * CHUNK;
#pragma unroll 4
    for (int j = 0; j < CHUNK / 256; j++) {
        int e = base + j * 256 + t;
        if (e < E) {
            int s = src[e];
            int d = dst[e];
            int pos = atomicAdd(&cur[d >> BSH], 1);
            ebuf[pos] = (s << BSH) | (d & (BSPAN - 1));
        }
    }
}

// ---------------------------------------------------------------------------
// Pass 3: per-bucket node-level CSR: rp, dinv, node-sorted esrc (plain src)
// ---------------------------------------------------------------------------
__global__ __launch_bounds__(256) void k_bucket_csr(const int* __restrict__ off,
                                                    const int* __restrict__ partials,
                                                    const int* __restrict__ ebuf,
                                                    int* __restrict__ rp,
                                                    float* __restrict__ dinv,
                                                    int* __restrict__ esrc,
                                                    int N, int NCH, int NBK, int S) {
    __shared__ int cnt[BSPAN];
    __shared__ int sh[BSPAN];
    int b = blockIdx.x, t = threadIdx.x;
    int bi = b * NCH;
    int base = off[bi] + partials[bi >> 10];
    int ei_  = (b + 1) * NCH;
    int end  = (ei_ == S) ? off[S] : (off[ei_] + partials[ei_ >> 10]);

    cnt[t] = 0;
    __syncthreads();
    for (int i = base + t; i < end; i += 256) atomicAdd(&cnt[ebuf[i] & (BSPAN - 1)], 1);
    __syncthreads();

    int c = cnt[t];
    sh[t] = c;
    __syncthreads();
    for (int o = 1; o < 256; o <<= 1) {
        int tv = (t >= o) ? sh[t - o] : 0;
        __syncthreads();
        sh[t] += tv;
        __syncthreads();
    }
    int excl = sh[t] - c;

    int node = (b << BSH) + t;
    if (node < N) {
        rp[node] = base + excl;
        dinv[node] = rsqrtf((float)(1 + c));
    }
    if (b == NBK - 1) {
        if (t == 0) rp[N] = end;
        if (t < 16) esrc[end + t] = 0;     // pad (loads are clamped anyway)
    }
    __syncthreads();

    cnt[t] = base + excl;
    __syncthreads();
    for (int i = base + t; i < end; i += 256) {
        int v = ebuf[i];
        int p = atomicAdd(&cnt[v & (BSPAN - 1)], 1);
        esrc[p] = v >> BSH;                // plain src index
    }
}

// ---------------------------------------------------------------------------
// GEMM1 (K=256, A fp32): LDS staging via global_load_lds(16B), double-buffered,
// seg-rotation swizzle. Output fp16 (scaled by dinv[row]).
// ---------------------------------------------------------------------------
__global__ __launch_bounds__(256) void k_gemm1(const float* __restrict__ A,
                                               const __bf16* __restrict__ BfH,
                                               const __bf16* __restrict__ BfL,
                                               const float* __restrict__ dinv,
                                               _Float16* __restrict__ C, int nrows) {
    constexpr int K = 256, KC = 64, NCHK = 4, NCH32 = 8;
    __shared__ float As[2][64 * KC];       // 2 x 16 KB

    const int t = threadIdx.x;
    const int wave = t >> 6, lane = t & 63;
    const int m = lane & 15, q = lane >> 4;
    const int row0 = blockIdx.x * 64;

    const int s_sub = lane >> 4;
    const int s_seg = lane & 15;

    auto stage = [&](int ch, int buf) {
#pragma unroll
        for (int j = 0; j < 4; j++) {
            int lr = wave * 16 + j * 4 + s_sub;
            int gr = row0 + lr; if (gr > nrows - 1) gr = nrows - 1;
            int gs = (s_seg - lr) & 15;
            const float* g = A + (size_t)gr * K + ch * KC + gs * 4;
            float* l = &As[buf][(size_t)lr * KC + s_seg * 4];
            __builtin_amdgcn_global_load_lds(
                (const __attribute__((address_space(1))) void*)g,
                (__attribute__((address_space(3))) void*)l, 16, 0, 0);
        }
    };

    floatx4 acc[4] = {{0.f, 0.f, 0.f, 0.f}, {0.f, 0.f, 0.f, 0.f},
                      {0.f, 0.f, 0.f, 0.f}, {0.f, 0.f, 0.f, 0.f}};

    stage(0, 0);
    __syncthreads();

    for (int ch = 0; ch < NCHK; ch++) {
        if (ch + 1 < NCHK) stage(ch + 1, (ch + 1) & 1);

        const float* arow = &As[ch & 1][(size_t)(wave * 16 + m) * KC];
#pragma unroll
        for (int jj = 0; jj < 2; jj++) {
            int ch2 = ch * 2 + jj;
            int s0 = jj * 8 + q * 2;
            float4 v0 = *(const float4*)(arow + (((s0 + m) & 15) * 4));
            float4 v1 = *(const float4*)(arow + (((s0 + 1 + m) & 15) * 4));
            float af[8] = {v0.x, v0.y, v0.z, v0.w, v1.x, v1.y, v1.z, v1.w};
            bf16x8 ah, al;
#pragma unroll
            for (int j = 0; j < 8; j++) {
                __bf16 h = (__bf16)af[j];
                ah[j] = h;
                al[j] = (__bf16)(af[j] - (float)h);
            }
#pragma unroll
            for (int c = 0; c < 4; c++) {
                const bf16x8 bh = *(const bf16x8*)(BfH + ((size_t)(c * NCH32 + ch2) * 64 + lane) * 8);
                const bf16x8 bl = *(const bf16x8*)(BfL + ((size_t)(c * NCH32 + ch2) * 64 + lane) * 8);
                acc[c] = __builtin_amdgcn_mfma_f32_16x16x32_bf16(ah, bh, acc[c], 0, 0, 0);
                acc[c] = __builtin_amdgcn_mfma_f32_16x16x32_bf16(al, bh, acc[c], 0, 0, 0);
                acc[c] = __builtin_amdgcn_mfma_f32_16x16x32_bf16(ah, bl, acc[c], 0, 0, 0);
            }
        }
        __syncthreads();
    }

#pragma unroll
    for (int i = 0; i < 4; i++) {
        int r = row0 + wave * 16 + q * 4 + i;
        if (r < nrows) {
            float di = dinv[r];
#pragma unroll
            for (int c = 0; c < 4; c++)
                C[(size_t)r * 64 + c * 16 + m] = (_Float16)(acc[c][i] * di);
        }
    }
}

// ---------------------------------------------------------------------------
// GEMM2 (K=64, A fp16): single 8 KB LDS stage, split-bf16 MFMA. Output fp16.
// ---------------------------------------------------------------------------
__global__ __launch_bounds__(256) void k_gemm2(const _Float16* __restrict__ A,
                                               const __bf16* __restrict__ BfH,
                                               const __bf16* __restrict__ BfL,
                                               const float* __restrict__ dinv,
                                               _Float16* __restrict__ C, int nrows) {
    __shared__ _Float16 As[64 * 64];       // 8 KB
    const int t = threadIdx.x;
    const int wave = t >> 6, lane = t & 63;
    const int m = lane & 15, q = lane >> 4;
    const int row0 = blockIdx.x * 64;

#pragma unroll
    for (int j = 0; j < 2; j++) {
        int lr = j * 32 + wave * 8 + (lane >> 3);
        int p  = lane & 7;
        int gr = row0 + lr; if (gr > nrows - 1) gr = nrows - 1;
        int gs = (p - lr) & 7;                          // rotated seg
        const _Float16* g = A + (size_t)gr * 64 + gs * 8;
        _Float16* l = &As[(size_t)lr * 64 + p * 8];
        __builtin_amdgcn_global_load_lds(
            (const __attribute__((address_space(1))) void*)g,
            (__attribute__((address_space(3))) void*)l, 16, 0, 0);
    }
    __syncthreads();

    floatx4 acc[4] = {{0.f, 0.f, 0.f, 0.f}, {0.f, 0.f, 0.f, 0.f},
                      {0.f, 0.f, 0.f, 0.f}, {0.f, 0.f, 0.f, 0.f}};

    const _Float16* arow = &As[(size_t)(wave * 16 + m) * 64];
#pragma unroll
    for (int jj = 0; jj < 2; jj++) {
        int s0 = jj * 4 + q;
        half8 v = *(const half8*)(arow + (((s0 + m) & 7) * 8));
        bf16x8 ah, al;
#pragma unroll
        for (int j = 0; j < 8; j++) {
            float f = (float)v[j];
            __bf16 h = (__bf16)f;
            ah[j] = h;
            al[j] = (__bf16)(f - (float)h);
        }
#pragma unroll
        for (int c = 0; c < 4; c++) {
            const bf16x8 bh = *(const bf16x8*)(BfH + ((size_t)(c * 2 + jj) * 64 + lane) * 8);
            const bf16x8 bl = *(const bf16x8*)(BfL + ((size_t)(c * 2 + jj) * 64 + lane) * 8);
            acc[c] = __builtin_amdgcn_mfma_f32_16x16x32_bf16(ah, bh, acc[c], 0, 0, 0);
            acc[c] = __builtin_amdgcn_mfma_f32_16x16x32_bf16(al, bh, acc[c], 0, 0, 0);
            acc[c] = __builtin_amdgcn_mfma_f32_16x16x32_bf16(ah, bl, acc[c], 0, 0, 0);
        }
    }

#pragma unroll
    for (int i = 0; i < 4; i++) {
        int r = row0 + wave * 16 + q * 4 + i;
        if (r < nrows) {
            float di = dinv[r];
#pragma unroll
            for (int c = 0; c < 4; c++)
                C[(size_t)r * 64 + c * 16 + m] = (_Float16)(acc[c][i] * di);
        }
    }
}

// ---------------------------------------------------------------------------
// Aggregation over CSR (round-1 structure, best measured): one wave per node,
// lane = (qe=lane>>4 edge slot, fg=lane&15 feature group), half4v 8 B loads,
// 16 edges in flight per iter, shfl_xor fold over slots.
// MODE 0: out[d] = relu fp16   MODE 1: h3[d] = (relu @ W3) * dinv[d] (fp32)
// ---------------------------------------------------------------------------
template <int MODE>
__global__ __launch_bounds__(256) void k_agg64(const _Float16* __restrict__ hs,
                                               const float* __restrict__ dinv,
                                               const int* __restrict__ rp,
                                               const int* __restrict__ esrc,
                                               const float* __restrict__ bias,
                                               const float* __restrict__ W3,
                                               void* __restrict__ out, int n) {
    int lane = threadIdx.x & 63;
    int qe = lane >> 4;          // edge slot 0..3
    int fg = lane & 15;          // feature group (4 consecutive feats)
    int nid = blockIdx.x * 4 + (threadIdx.x >> 6);
    if (nid >= n) return;
    nid = __builtin_amdgcn_readfirstlane(nid);

    float dii = dinv[nid];
    int e0 = rp[nid];
    int e1 = rp[nid + 1];
    int last = e1 - 1;

    float a0 = 0.f, a1 = 0.f, a2 = 0.f, a3 = 0.f;
    // self term (counted once: only edge-slot 0)
    if (qe == 0) {
        half4v sv = *(const half4v*)(hs + (size_t)nid * 64 + fg * 4);
        a0 = (float)sv[0]; a1 = (float)sv[1]; a2 = (float)sv[2]; a3 = (float)sv[3];
    }

    for (int e = e0; e <= last; e += 16) {
#pragma unroll
        for (int u = 0; u < 4; u++) {
            int slot = e + u * 4 + qe;
            int idx = esrc[min(slot, last)];
            half4v v = *(const half4v*)(hs + (size_t)idx * 64 + fg * 4);
            if (slot <= last) {
                a0 += (float)v[0]; a1 += (float)v[1];
                a2 += (float)v[2]; a3 += (float)v[3];
            }
        }
    }

    // fold the 4 edge slots: after masks 16 and 32 every lane holds the sum
#pragma unroll
    for (int o = 16; o <= 32; o <<= 1) {
        a0 += __shfl_xor(a0, o, 64);
        a1 += __shfl_xor(a1, o, 64);
        a2 += __shfl_xor(a2, o, 64);
        a3 += __shfl_xor(a3, o, 64);
    }

    float4 b4 = ((const float4*)bias)[fg];
    a0 = fmaxf(a0 * dii + b4.x, 0.f);
    a1 = fmaxf(a1 * dii + b4.y, 0.f);
    a2 = fmaxf(a2 * dii + b4.z, 0.f);
    a3 = fmaxf(a3 * dii + b4.w, 0.f);

    if (MODE == 0) {
        if (qe == 0) {
            half4v o4;
            o4[0] = (_Float16)a0; o4[1] = (_Float16)a1;
            o4[2] = (_Float16)a2; o4[3] = (_Float16)a3;
            *(half4v*)((_Float16*)out + (size_t)nid * 64 + fg * 4) = o4;
        }
    } else {
        const float2* w3 = (const float2*)W3;
        float2 w0 = w3[fg * 4 + 0], w1 = w3[fg * 4 + 1];
        float2 w2 = w3[fg * 4 + 2], w3v = w3[fg * 4 + 3];
        float p0 = a0 * w0.x + a1 * w1.x + a2 * w2.x + a3 * w3v.x;
        float p1 = a0 * w0.y + a1 * w1.y + a2 * w2.y + a3 * w3v.y;
#pragma unroll
        for (int o = 1; o <= 8; o <<= 1) {
            p0 += __shfl_xor(p0, o, 64);
            p1 += __shfl_xor(p1, o, 64);
        }
        if (lane == 0) ((float2*)out)[nid] = make_float2(p0 * dii, p1 * dii);
    }
}

// ---------------------------------------------------------------------------
// Final layer: 2-wide aggregation + bias + log_softmax (thread per node)
// ---------------------------------------------------------------------------
__global__ __launch_bounds__(256) void k_final(const float2* __restrict__ h3s,
                                               const float* __restrict__ dinv,
                                               const int* __restrict__ rp,
                                               const int* __restrict__ esrc,
                                               const float* __restrict__ b3,
                                               float* __restrict__ out, int n) {
    int i = blockIdx.x * blockDim.x + threadIdx.x;
    if (i >= n) return;
    float dii = dinv[i];
    float2 h = h3s[i];
    float ax = h.x, ay = h.y;
    float bx = 0.f, by = 0.f, cx = 0.f, cy = 0.f, dx = 0.f, dy = 0.f;
    int e0 = rp[i], e1 = rp[i + 1];
    for (int e = e0; e < e1; e += 4) {
        int last = e1 - 1;
        int s0 = esrc[e];
        int s1 = esrc[min(e + 1, last)];
        int s2 = esrc[min(e + 2, last)];
        int s3 = esrc[min(e + 3, last)];
        float2 v0 = h3s[s0];
        float2 v1 = h3s[s1];
        float2 v2 = h3s[s2];
        float2 v3 = h3s[s3];
        ax += v0.x; ay += v0.y;
        bx += (e + 1 <= last) ? v1.x : 0.f; by += (e + 1 <= last) ? v1.y : 0.f;
        cx += (e + 2 <= last) ? v2.x : 0.f; cy += (e + 2 <= last) ? v2.y : 0.f;
        dx += (e + 3 <= last) ? v3.x : 0.f; dy += (e + 3 <= last) ? v3.y : 0.f;
    }
    float l0 = ((ax + bx) + (cx + dx)) * dii + b3[0];
    float l1 = ((ay + by) + (cy + dy)) * dii + b3[1];
    float mx = fmaxf(l0, l1);
    float lse = mx + log1pf(__expf(-fabsf(l0 - l1)));
    ((float2*)out)[i] = make_float2(l0 - lse, l1 - lse);
}

// ---------------------------------------------------------------------------
// Launch
// ---------------------------------------------------------------------------
extern "C" void kernel_launch(void* const* d_in, const int* in_sizes, int n_in,
                              void* d_out, int out_size, void* d_ws, size_t ws_size,
                              hipStream_t stream) {
    const float* x   = (const float*)d_in[0];
    const int*   ei  = (const int*)d_in[1];
    const float* W1  = (const float*)d_in[2];
    const float* b1  = (const float*)d_in[3];
    const float* W2  = (const float*)d_in[4];
    const float* b2  = (const float*)d_in[5];
    const float* W3  = (const float*)d_in[6];
    const float* b3  = (const float*)d_in[7];
    float* out = (float*)d_out;

    const int N = in_sizes[0] / F_IN;   // 100000
    const int E = in_sizes[1] / 2;      // 1600000
    const int* src = ei;
    const int* dst = ei + E;

    const int NBK = (N + BSPAN - 1) / BSPAN;      // 391
    const int NCH = (E + CHUNK - 1) / CHUNK;      // 391
    const int S   = NBK * NCH;

    // workspace bump allocator (256B aligned)
    char* p = (char*)d_ws;
    auto alloc = [&](size_t bytes) -> void* {
        void* r = (void*)p;
        p += (bytes + 255) & ~(size_t)255;
        return r;
    };
    int*      cntT     = (int*)alloc((size_t)S * 4);
    int*      off      = (int*)alloc((size_t)(S + 1) * 4);
    int*      partials = (int*)alloc(4096);
    int*      ebuf     = (int*)alloc((size_t)E * 4);
    int*      esrc     = (int*)alloc((size_t)(E + 64) * 4);   // +pad
    int*      rp       = (int*)alloc((size_t)(N + 1) * 4);
    float*    dinv     = (float*)alloc((size_t)N * 4);
    _Float16* bufA     = (_Float16*)alloc((size_t)N * HID * 2);
    _Float16* bufB     = (_Float16*)alloc((size_t)N * HID * 2);
    float*    h3       = (float*)alloc((size_t)N * 2 * 4);
    __bf16*   f1h      = (__bf16*)alloc(16384 * 2);
    __bf16*   f1l      = (__bf16*)alloc(16384 * 2);
    __bf16*   f2h      = (__bf16*)alloc(4096 * 2);
    __bf16*   f2l      = (__bf16*)alloc(4096 * 2);

    const int T = 256;
    int scanBlocks = (S + 1023) / 1024;

    // CSR build (hist fused with weight prep); scanC folded into consumers
    k_pre<<<NCH, T, 0, stream>>>(dst, cntT, E, NCH, NBK, W1, f1h, f1l, W2, f2h, f2l);
    k_scanA<<<scanBlocks, T, 0, stream>>>(cntT, off, partials, S);
    k_scanB<<<1, 64, 0, stream>>>(partials, off, scanBlocks, S);
    k_sortwrite<<<NCH, T, 0, stream>>>(src, dst, off, partials, ebuf, E, NCH, NBK);
    k_bucket_csr<<<NBK, T, 0, stream>>>(off, partials, ebuf, rp, dinv, esrc, N, NCH, NBK, S);

    // layer 1
    int gemmBlocks = (N + 63) / 64;
    k_gemm1<<<gemmBlocks, T, 0, stream>>>(x, f1h, f1l, dinv, bufA, N);
    k_agg64<0><<<(N + 3) / 4, T, 0, stream>>>(bufA, dinv, rp, esrc, b1, nullptr, bufB, N);

    // layer 2 (+ fused GEMM3 in agg)
    k_gemm2<<<gemmBlocks, T, 0, stream>>>(bufB, f2h, f2l, dinv, bufA, N);
    k_agg64<1><<<(N + 3) / 4, T, 0, stream>>>(bufA, dinv, rp, esrc, b2, W3, h3, N);

    // layer 3 + log_softmax
    k_final<<<(N + T - 1) / T, T, 0, stream>>>((const float2*)h3, dinv, rp, esrc, b3, out, N);
}

// Round 9
// 378.385 us; speedup vs baseline: 1.3736x; 1.0645x over previous
//
#include <hip/hip_runtime.h>
#include <math.h>

#define F_IN 256
#define HID  64
#define BSH  8              // bucket = dst >> 8 (256 nodes per bucket)
#define BSPAN 256
#define CHUNK 4096          // edges per sort block (16 per thread)
#define NBK_MAX 512

typedef __bf16   bf16x8 __attribute__((ext_vector_type(8)));
typedef float    floatx4 __attribute__((ext_vector_type(4)));
typedef _Float16 half8 __attribute__((ext_vector_type(8)));
typedef _Float16 half4v __attribute__((ext_vector_type(4)));

// ---------------------------------------------------------------------------
// Fused pass: per-chunk histogram over coarse dst buckets + (blocks 0..7)
// weight prep W[K x 64] -> split-bf16 MFMA fragment layout.
// ---------------------------------------------------------------------------
__global__ __launch_bounds__(256) void k_pre(const int* __restrict__ dst,
                                             int* __restrict__ cntT,
                                             int E, int NCH, int NBK,
                                             const float* __restrict__ W1,
                                             __bf16* __restrict__ f1h, __bf16* __restrict__ f1l,
                                             const float* __restrict__ W2,
                                             __bf16* __restrict__ f2h, __bf16* __restrict__ f2l) {
    __shared__ int hist[NBK_MAX];
    int t = threadIdx.x, c = blockIdx.x;
    hist[t] = 0; hist[t + 256] = 0;
    __syncthreads();
    int base = c * CHUNK;
#pragma unroll 4
    for (int j = 0; j < CHUNK / 256; j++) {
        int e = base + j * 256 + t;
        if (e < E) atomicAdd(&hist[dst[e] >> BSH], 1);
    }
    __syncthreads();
    for (int b = t; b < NBK; b += 256) cntT[b * NCH + c] = hist[b];

    if (c < 8) {
        int g = c * 256 + t;                      // 0..2047
        for (int idx = g; idx < 16384; idx += 2048) {
            int j = idx & 7, lane = (idx >> 3) & 63, ch2 = (idx >> 9) & 7, cc = idx >> 12;
            int k = ch2 * 32 + (lane >> 4) * 8 + j, col = cc * 16 + (lane & 15);
            float w = W1[k * 64 + col];
            __bf16 h = (__bf16)w;
            f1h[idx] = h; f1l[idx] = (__bf16)(w - (float)h);
        }
        for (int idx = g; idx < 4096; idx += 2048) {
            int j = idx & 7, lane = (idx >> 3) & 63, ch2 = (idx >> 9) & 1, cc = idx >> 10;
            int k = ch2 * 32 + (lane >> 4) * 8 + j, col = cc * 16 + (lane & 15);
            float w = W2[k * 64 + col];
            __bf16 h = (__bf16)w;
            f2h[idx] = h; f2l[idx] = (__bf16)(w - (float)h);
        }
    }
}

// ---------------------------------------------------------------------------
// Exclusive scan of cntT (S elements) -> off (block-local) + partials
// ---------------------------------------------------------------------------
__global__ __launch_bounds__(256) void k_scanA(const int* __restrict__ cntT,
                                               int* __restrict__ off,
                                               int* __restrict__ partials, int S) {
    __shared__ int sh[256];
    int tid = threadIdx.x;
    int base = blockIdx.x * 1024 + tid * 4;
    int v[4];
    int s = 0;
#pragma unroll
    for (int j = 0; j < 4; j++) {
        int idx = base + j;
        v[j] = (idx < S) ? cntT[idx] : 0;
        s += v[j];
    }
    sh[tid] = s;
    __syncthreads();
    int mysum = s;
    for (int o = 1; o < 256; o <<= 1) {
        int tv = (tid >= o) ? sh[tid - o] : 0;
        __syncthreads();
        sh[tid] += tv;
        __syncthreads();
    }
    int pref = sh[tid] - mysum;
#pragma unroll
    for (int j = 0; j < 4; j++) {
        int idx = base + j;
        if (idx < S) off[idx] = pref;
        pref += v[j];
    }
    if (tid == 255) partials[blockIdx.x] = sh[255];
}

__global__ void k_scanB(int* __restrict__ partials, int* __restrict__ off,
                        int nblk, int S) {
    if (blockIdx.x == 0 && threadIdx.x == 0) {
        int run = 0;
        for (int b = 0; b < nblk; b++) { int t = partials[b]; partials[b] = run; run += t; }
        off[S] = run;   // == E (absolute sentinel)
    }
}

// ---------------------------------------------------------------------------
// Pass 2: scatter edges into bucket-grouped ebuf. Entry = (src<<8)|(dst&255)
// (partial-add folded in: off[] is block-local, + partials[idx>>10])
// ---------------------------------------------------------------------------
__global__ __launch_bounds__(256) void k_sortwrite(const int* __restrict__ src,
                                                   const int* __restrict__ dst,
                                                   const int* __restrict__ off,
                                                   const int* __restrict__ partials,
                                                   int* __restrict__ ebuf,
                                                   int E, int NCH, int NBK) {
    __shared__ int cur[NBK_MAX];
    int t = threadIdx.x, c = blockIdx.x;
    for (int b = t; b < NBK; b += 256) {
        int idx = b * NCH + c;
        cur[b] = off[idx] + partials[idx >> 10];
    }
    __syncthreads();
    int base = c * CHUNK;
#pragma unroll 4
    for (int j = 0; j < CHUNK / 256; j++) {
        int e = base + j * 256 + t;
        if (e < E) {
            int s = src[e];
            int d = dst[e];
            int pos = atomicAdd(&cur[d >> BSH], 1);
            ebuf[pos] = (s << BSH) | (d & (BSPAN - 1));
        }
    }
}

// ---------------------------------------------------------------------------
// Pass 3: per-bucket node-level CSR: rp, dinv, node-sorted esrc (plain src)
// ---------------------------------------------------------------------------
__global__ __launch_bounds__(256) void k_bucket_csr(const int* __restrict__ off,
                                                    const int* __restrict__ partials,
                                                    const int* __restrict__ ebuf,
                                                    int* __restrict__ rp,
                                                    float* __restrict__ dinv,
                                                    int* __restrict__ esrc,
                                                    int N, int NCH, int NBK, int S) {
    __shared__ int cnt[BSPAN];
    __shared__ int sh[BSPAN];
    int b = blockIdx.x, t = threadIdx.x;
    int bi = b * NCH;
    int base = off[bi] + partials[bi >> 10];
    int ei_  = (b + 1) * NCH;
    int end  = (ei_ == S) ? off[S] : (off[ei_] + partials[ei_ >> 10]);

    cnt[t] = 0;
    __syncthreads();
    for (int i = base + t; i < end; i += 256) atomicAdd(&cnt[ebuf[i] & (BSPAN - 1)], 1);
    __syncthreads();

    int c = cnt[t];
    sh[t] = c;
    __syncthreads();
    for (int o = 1; o < 256; o <<= 1) {
        int tv = (t >= o) ? sh[t - o] : 0;
        __syncthreads();
        sh[t] += tv;
        __syncthreads();
    }
    int excl = sh[t] - c;

    int node = (b << BSH) + t;
    if (node < N) {
        rp[node] = base + excl;
        dinv[node] = rsqrtf((float)(1 + c));
    }
    if (b == NBK - 1) {
        if (t == 0) rp[N] = end;
        if (t < 16) esrc[end + t] = 0;     // pad (loads are clamped anyway)
    }
    __syncthreads();

    cnt[t] = base + excl;
    __syncthreads();
    for (int i = base + t; i < end; i += 256) {
        int v = ebuf[i];
        int p = atomicAdd(&cnt[v & (BSPAN - 1)], 1);
        esrc[p] = v >> BSH;                // plain src index
    }
}

// ---------------------------------------------------------------------------
// GEMM1 (K=256, A fp32): LDS staging via global_load_lds(16B), double-buffered,
// seg-rotation swizzle. Output fp16 (scaled by dinv[row]).
// ---------------------------------------------------------------------------
__global__ __launch_bounds__(256) void k_gemm1(const float* __restrict__ A,
                                               const __bf16* __restrict__ BfH,
                                               const __bf16* __restrict__ BfL,
                                               const float* __restrict__ dinv,
                                               _Float16* __restrict__ C, int nrows) {
    constexpr int K = 256, KC = 64, NCHK = 4, NCH32 = 8;
    __shared__ float As[2][64 * KC];       // 2 x 16 KB

    const int t = threadIdx.x;
    const int wave = t >> 6, lane = t & 63;
    const int m = lane & 15, q = lane >> 4;
    const int row0 = blockIdx.x * 64;

    const int s_sub = lane >> 4;
    const int s_seg = lane & 15;

    auto stage = [&](int ch, int buf) {
#pragma unroll
        for (int j = 0; j < 4; j++) {
            int lr = wave * 16 + j * 4 + s_sub;
            int gr = row0 + lr; if (gr > nrows - 1) gr = nrows - 1;
            int gs = (s_seg - lr) & 15;
            const float* g = A + (size_t)gr * K + ch * KC + gs * 4;
            float* l = &As[buf][(size_t)lr * KC + s_seg * 4];
            __builtin_amdgcn_global_load_lds(
                (const __attribute__((address_space(1))) void*)g,
                (__attribute__((address_space(3))) void*)l, 16, 0, 0);
        }
    };

    floatx4 acc[4] = {{0.f, 0.f, 0.f, 0.f}, {0.f, 0.f, 0.f, 0.f},
                      {0.f, 0.f, 0.f, 0.f}, {0.f, 0.f, 0.f, 0.f}};

    stage(0, 0);
    __syncthreads();

    for (int ch = 0; ch < NCHK; ch++) {
        if (ch + 1 < NCHK) stage(ch + 1, (ch + 1) & 1);

        const float* arow = &As[ch & 1][(size_t)(wave * 16 + m) * KC];
#pragma unroll
        for (int jj = 0; jj < 2; jj++) {
            int ch2 = ch * 2 + jj;
            int s0 = jj * 8 + q * 2;
            float4 v0 = *(const float4*)(arow + (((s0 + m) & 15) * 4));
            float4 v1 = *(const float4*)(arow + (((s0 + 1 + m) & 15) * 4));
            float af[8] = {v0.x, v0.y, v0.z, v0.w, v1.x, v1.y, v1.z, v1.w};
            bf16x8 ah, al;
#pragma unroll
            for (int j = 0; j < 8; j++) {
                __bf16 h = (__bf16)af[j];
                ah[j] = h;
                al[j] = (__bf16)(af[j] - (float)h);
            }
#pragma unroll
            for (int c = 0; c < 4; c++) {
                const bf16x8 bh = *(const bf16x8*)(BfH + ((size_t)(c * NCH32 + ch2) * 64 + lane) * 8);
                const bf16x8 bl = *(const bf16x8*)(BfL + ((size_t)(c * NCH32 + ch2) * 64 + lane) * 8);
                acc[c] = __builtin_amdgcn_mfma_f32_16x16x32_bf16(ah, bh, acc[c], 0, 0, 0);
                acc[c] = __builtin_amdgcn_mfma_f32_16x16x32_bf16(al, bh, acc[c], 0, 0, 0);
                acc[c] = __builtin_amdgcn_mfma_f32_16x16x32_bf16(ah, bl, acc[c], 0, 0, 0);
            }
        }
        __syncthreads();
    }

#pragma unroll
    for (int i = 0; i < 4; i++) {
        int r = row0 + wave * 16 + q * 4 + i;
        if (r < nrows) {
            float di = dinv[r];
#pragma unroll
            for (int c = 0; c < 4; c++)
                C[(size_t)r * 64 + c * 16 + m] = (_Float16)(acc[c][i] * di);
        }
    }
}

// ---------------------------------------------------------------------------
// GEMM2 (K=64, A fp16): single 8 KB LDS stage, split-bf16 MFMA. Output fp16.
// ---------------------------------------------------------------------------
__global__ __launch_bounds__(256) void k_gemm2(const _Float16* __restrict__ A,
                                               const __bf16* __restrict__ BfH,
                                               const __bf16* __restrict__ BfL,
                                               const float* __restrict__ dinv,
                                               _Float16* __restrict__ C, int nrows) {
    __shared__ _Float16 As[64 * 64];       // 8 KB
    const int t = threadIdx.x;
    const int wave = t >> 6, lane = t & 63;
    const int m = lane & 15, q = lane >> 4;
    const int row0 = blockIdx.x * 64;

#pragma unroll
    for (int j = 0; j < 2; j++) {
        int lr = j * 32 + wave * 8 + (lane >> 3);
        int p  = lane & 7;
        int gr = row0 + lr; if (gr > nrows - 1) gr = nrows - 1;
        int gs = (p - lr) & 7;                          // rotated seg
        const _Float16* g = A + (size_t)gr * 64 + gs * 8;
        _Float16* l = &As[(size_t)lr * 64 + p * 8];
        __builtin_amdgcn_global_load_lds(
            (const __attribute__((address_space(1))) void*)g,
            (__attribute__((address_space(3))) void*)l, 16, 0, 0);
    }
    __syncthreads();

    floatx4 acc[4] = {{0.f, 0.f, 0.f, 0.f}, {0.f, 0.f, 0.f, 0.f},
                      {0.f, 0.f, 0.f, 0.f}, {0.f, 0.f, 0.f, 0.f}};

    const _Float16* arow = &As[(size_t)(wave * 16 + m) * 64];
#pragma unroll
    for (int jj = 0; jj < 2; jj++) {
        int s0 = jj * 4 + q;
        half8 v = *(const half8*)(arow + (((s0 + m) & 7) * 8));
        bf16x8 ah, al;
#pragma unroll
        for (int j = 0; j < 8; j++) {
            float f = (float)v[j];
            __bf16 h = (__bf16)f;
            ah[j] = h;
            al[j] = (__bf16)(f - (float)h);
        }
#pragma unroll
        for (int c = 0; c < 4; c++) {
            const bf16x8 bh = *(const bf16x8*)(BfH + ((size_t)(c * 2 + jj) * 64 + lane) * 8);
            const bf16x8 bl = *(const bf16x8*)(BfL + ((size_t)(c * 2 + jj) * 64 + lane) * 8);
            acc[c] = __builtin_amdgcn_mfma_f32_16x16x32_bf16(ah, bh, acc[c], 0, 0, 0);
            acc[c] = __builtin_amdgcn_mfma_f32_16x16x32_bf16(al, bh, acc[c], 0, 0, 0);
            acc[c] = __builtin_amdgcn_mfma_f32_16x16x32_bf16(ah, bl, acc[c], 0, 0, 0);
        }
    }

#pragma unroll
    for (int i = 0; i < 4; i++) {
        int r = row0 + wave * 16 + q * 4 + i;
        if (r < nrows) {
            float di = dinv[r];
#pragma unroll
            for (int c = 0; c < 4; c++)
                C[(size_t)r * 64 + c * 16 + m] = (_Float16)(acc[c][i] * di);
        }
    }
}

// ---------------------------------------------------------------------------
// Aggregation over CSR (round-1 layout): one wave per node, lane = (qe edge
// slot, fg feature group), half4v 8 B loads. NEW: the 4 esrc loads and the
// 4 gathers are issued as a block and PINNED before the accumulates with
// sched_barrier(0), forcing 16 cache lines in flight per wave (VGPR 16 -> ~36)
// instead of the compiler's register-minimal 1-2.
// MODE 0: out[d] = relu fp16   MODE 1: h3[d] = (relu @ W3) * dinv[d] (fp32)
// ---------------------------------------------------------------------------
template <int MODE>
__global__ __launch_bounds__(256) void k_agg64(const _Float16* __restrict__ hs,
                                               const float* __restrict__ dinv,
                                               const int* __restrict__ rp,
                                               const int* __restrict__ esrc,
                                               const float* __restrict__ bias,
                                               const float* __restrict__ W3,
                                               void* __restrict__ out, int n) {
    int lane = threadIdx.x & 63;
    int qe = lane >> 4;          // edge slot 0..3
    int fg = lane & 15;          // feature group (4 consecutive feats)
    int nid = blockIdx.x * 4 + (threadIdx.x >> 6);
    if (nid >= n) return;
    nid = __builtin_amdgcn_readfirstlane(nid);

    float dii = dinv[nid];
    int e0 = rp[nid];
    int e1 = rp[nid + 1];
    int last = e1 - 1;

    float a0 = 0.f, a1 = 0.f, a2 = 0.f, a3 = 0.f;
    // self term (counted once: only edge-slot 0)
    if (qe == 0) {
        half4v sv = *(const half4v*)(hs + (size_t)nid * 64 + fg * 4);
        a0 = (float)sv[0]; a1 = (float)sv[1]; a2 = (float)sv[2]; a3 = (float)sv[3];
    }

    for (int e = e0; e <= last; e += 16) {
        // ---- load block: 4 esrc + 4 gathers, all issued before any use
        int idx[4];
#pragma unroll
        for (int u = 0; u < 4; u++)
            idx[u] = esrc[min(e + u * 4 + qe, last)];
        half4v v[4];
#pragma unroll
        for (int u = 0; u < 4; u++)
            v[u] = *(const half4v*)(hs + (size_t)idx[u] * 64 + fg * 4);
        __builtin_amdgcn_sched_barrier(0);   // pin: no accumulate hoists above
        // ---- accumulate block
#pragma unroll
        for (int u = 0; u < 4; u++) {
            if (e + u * 4 + qe <= last) {
                a0 += (float)v[u][0]; a1 += (float)v[u][1];
                a2 += (float)v[u][2]; a3 += (float)v[u][3];
            }
        }
    }

    // fold the 4 edge slots: after masks 16 and 32 every lane holds the sum
#pragma unroll
    for (int o = 16; o <= 32; o <<= 1) {
        a0 += __shfl_xor(a0, o, 64);
        a1 += __shfl_xor(a1, o, 64);
        a2 += __shfl_xor(a2, o, 64);
        a3 += __shfl_xor(a3, o, 64);
    }

    float4 b4 = ((const float4*)bias)[fg];
    a0 = fmaxf(a0 * dii + b4.x, 0.f);
    a1 = fmaxf(a1 * dii + b4.y, 0.f);
    a2 = fmaxf(a2 * dii + b4.z, 0.f);
    a3 = fmaxf(a3 * dii + b4.w, 0.f);

    if (MODE == 0) {
        if (qe == 0) {
            half4v o4;
            o4[0] = (_Float16)a0; o4[1] = (_Float16)a1;
            o4[2] = (_Float16)a2; o4[3] = (_Float16)a3;
            *(half4v*)((_Float16*)out + (size_t)nid * 64 + fg * 4) = o4;
        }
    } else {
        const float2* w3 = (const float2*)W3;
        float2 w0 = w3[fg * 4 + 0], w1 = w3[fg * 4 + 1];
        float2 w2 = w3[fg * 4 + 2], w3v = w3[fg * 4 + 3];
        float p0 = a0 * w0.x + a1 * w1.x + a2 * w2.x + a3 * w3v.x;
        float p1 = a0 * w0.y + a1 * w1.y + a2 * w2.y + a3 * w3v.y;
#pragma unroll
        for (int o = 1; o <= 8; o <<= 1) {
            p0 += __shfl_xor(p0, o, 64);
            p1 += __shfl_xor(p1, o, 64);
        }
        if (lane == 0) ((float2*)out)[nid] = make_float2(p0 * dii, p1 * dii);
    }
}

// ---------------------------------------------------------------------------
// Final layer: 2-wide aggregation + bias + log_softmax (thread per node)
// ---------------------------------------------------------------------------
__global__ __launch_bounds__(256) void k_final(const float2* __restrict__ h3s,
                                               const float* __restrict__ dinv,
                                               const int* __restrict__ rp,
                                               const int* __restrict__ esrc,
                                               const float* __restrict__ b3,
                                               float* __restrict__ out, int n) {
    int i = blockIdx.x * blockDim.x + threadIdx.x;
    if (i >= n) return;
    float dii = dinv[i];
    float2 h = h3s[i];
    float ax = h.x, ay = h.y;
    float bx = 0.f, by = 0.f, cx = 0.f, cy = 0.f, dx = 0.f, dy = 0.f;
    int e0 = rp[i], e1 = rp[i + 1];
    for (int e = e0; e < e1; e += 4) {
        int last = e1 - 1;
        int s0 = esrc[e];
        int s1 = esrc[min(e + 1, last)];
        int s2 = esrc[min(e + 2, last)];
        int s3 = esrc[min(e + 3, last)];
        float2 v0 = h3s[s0];
        float2 v1 = h3s[s1];
        float2 v2 = h3s[s2];
        float2 v3 = h3s[s3];
        ax += v0.x; ay += v0.y;
        bx += (e + 1 <= last) ? v1.x : 0.f; by += (e + 1 <= last) ? v1.y : 0.f;
        cx += (e + 2 <= last) ? v2.x : 0.f; cy += (e + 2 <= last) ? v2.y : 0.f;
        dx += (e + 3 <= last) ? v3.x : 0.f; dy += (e + 3 <= last) ? v3.y : 0.f;
    }
    float l0 = ((ax + bx) + (cx + dx)) * dii + b3[0];
    float l1 = ((ay + by) + (cy + dy)) * dii + b3[1];
    float mx = fmaxf(l0, l1);
    float lse = mx + log1pf(__expf(-fabsf(l0 - l1)));
    ((float2*)out)[i] = make_float2(l0 - lse, l1 - lse);
}

// ---------------------------------------------------------------------------
// Launch
// ---------------------------------------------------------------------------
extern "C" void kernel_launch(void* const* d_in, const int* in_sizes, int n_in,
                              void* d_out, int out_size, void* d_ws, size_t ws_size,
                              hipStream_t stream) {
    const float* x   = (const float*)d_in[0];
    const int*   ei  = (const int*)d_in[1];
    const float* W1  = (const float*)d_in[2];
    const float* b1  = (const float*)d_in[3];
    const float* W2  = (const float*)d_in[4];
    const float* b2  = (const float*)d_in[5];
    const float* W3  = (const float*)d_in[6];
    const float* b3  = (const float*)d_in[7];
    float* out = (float*)d_out;

    const int N = in_sizes[0] / F_IN;   // 100000
    const int E = in_sizes[1] / 2;      // 1600000
    const int* src = ei;
    const int* dst = ei + E;

    const int NBK = (N + BSPAN - 1) / BSPAN;      // 391
    const int NCH = (E + CHUNK - 1) / CHUNK;      // 391
    const int S   = NBK * NCH;

    // workspace bump allocator (256B aligned)
    char* p = (char*)d_ws;
    auto alloc = [&](size_t bytes) -> void* {
        void* r = (void*)p;
        p += (bytes + 255) & ~(size_t)255;
        return r;
    };
    int*      cntT     = (int*)alloc((size_t)S * 4);
    int*      off      = (int*)alloc((size_t)(S + 1) * 4);
    int*      partials = (int*)alloc(4096);
    int*      ebuf     = (int*)alloc((size_t)E * 4);
    int*      esrc     = (int*)alloc((size_t)(E + 64) * 4);   // +pad
    int*      rp       = (int*)alloc((size_t)(N + 1) * 4);
    float*    dinv     = (float*)alloc((size_t)N * 4);
    _Float16* bufA     = (_Float16*)alloc((size_t)N * HID * 2);
    _Float16* bufB     = (_Float16*)alloc((size_t)N * HID * 2);
    float*    h3       = (float*)alloc((size_t)N * 2 * 4);
    __bf16*   f1h      = (__bf16*)alloc(16384 * 2);
    __bf16*   f1l      = (__bf16*)alloc(16384 * 2);
    __bf16*   f2h      = (__bf16*)alloc(4096 * 2);
    __bf16*   f2l      = (__bf16*)alloc(4096 * 2);

    const int T = 256;
    int scanBlocks = (S + 1023) / 1024;

    // CSR build (hist fused with weight prep); scanC folded into consumers
    k_pre<<<NCH, T, 0, stream>>>(dst, cntT, E, NCH, NBK, W1, f1h, f1l, W2, f2h, f2l);
    k_scanA<<<scanBlocks, T, 0, stream>>>(cntT, off, partials, S);
    k_scanB<<<1, 64, 0, stream>>>(partials, off, scanBlocks, S);
    k_sortwrite<<<NCH, T, 0, stream>>>(src, dst, off, partials, ebuf, E, NCH, NBK);
    k_bucket_csr<<<NBK, T, 0, stream>>>(off, partials, ebuf, rp, dinv, esrc, N, NCH, NBK, S);

    // layer 1
    int gemmBlocks = (N + 63) / 64;
    k_gemm1<<<gemmBlocks, T, 0, stream>>>(x, f1h, f1l, dinv, bufA, N);
    k_agg64<0><<<(N + 3) / 4, T, 0, stream>>>(bufA, dinv, rp, esrc, b1, nullptr, bufB, N);

    // layer 2 (+ fused GEMM3 in agg)
    k_gemm2<<<gemmBlocks, T, 0, stream>>>(bufB, f2h, f2l, dinv, bufA, N);
    k_agg64<1><<<(N + 3) / 4, T, 0, stream>>>(bufA, dinv, rp, esrc, b2, W3, h3, N);

    // layer 3 + log_softmax
    k_final<<<(N + T - 1) / T, T, 0, stream>>>((const float2*)h3, dinv, rp, esrc, b3, out, N);
}

// Round 10
// 373.865 us; speedup vs baseline: 1.3902x; 1.0121x over previous
//
#include <hip/hip_runtime.h>
#include <math.h>

#define F_IN 256
#define HID  64
#define BSH  8              // bucket = dst >> 8 (256 nodes per bucket)
#define BSPAN 256
#define CHUNK 4096          // edges per sort block (16 per thread)
#define NBK_MAX 512

typedef __bf16   bf16x8 __attribute__((ext_vector_type(8)));
typedef float    floatx4 __attribute__((ext_vector_type(4)));
typedef _Float16 half8 __attribute__((ext_vector_type(8)));
typedef _Float16 half4v __attribute__((ext_vector_type(4)));

// ---------------------------------------------------------------------------
// Fused pass: per-chunk histogram over coarse dst buckets + (blocks 0..7)
// weight prep W[K x 64] -> split-bf16 MFMA fragment layout.
// ---------------------------------------------------------------------------
__global__ __launch_bounds__(256) void k_pre(const int* __restrict__ dst,
                                             int* __restrict__ cntT,
                                             int E, int NCH, int NBK,
                                             const float* __restrict__ W1,
                                             __bf16* __restrict__ f1h, __bf16* __restrict__ f1l,
                                             const float* __restrict__ W2,
                                             __bf16* __restrict__ f2h, __bf16* __restrict__ f2l) {
    __shared__ int hist[NBK_MAX];
    int t = threadIdx.x, c = blockIdx.x;
    hist[t] = 0; hist[t + 256] = 0;
    __syncthreads();
    int base = c * CHUNK;
#pragma unroll 4
    for (int j = 0; j < CHUNK / 256; j++) {
        int e = base + j * 256 + t;
        if (e < E) atomicAdd(&hist[dst[e] >> BSH], 1);
    }
    __syncthreads();
    for (int b = t; b < NBK; b += 256) cntT[b * NCH + c] = hist[b];

    if (c < 8) {
        int g = c * 256 + t;                      // 0..2047
        for (int idx = g; idx < 16384; idx += 2048) {
            int j = idx & 7, lane = (idx >> 3) & 63, ch2 = (idx >> 9) & 7, cc = idx >> 12;
            int k = ch2 * 32 + (lane >> 4) * 8 + j, col = cc * 16 + (lane & 15);
            float w = W1[k * 64 + col];
            __bf16 h = (__bf16)w;
            f1h[idx] = h; f1l[idx] = (__bf16)(w - (float)h);
        }
        for (int idx = g; idx < 4096; idx += 2048) {
            int j = idx & 7, lane = (idx >> 3) & 63, ch2 = (idx >> 9) & 1, cc = idx >> 10;
            int k = ch2 * 32 + (lane >> 4) * 8 + j, col = cc * 16 + (lane & 15);
            float w = W2[k * 64 + col];
            __bf16 h = (__bf16)w;
            f2h[idx] = h; f2l[idx] = (__bf16)(w - (float)h);
        }
    }
}

// ---------------------------------------------------------------------------
// Exclusive scan of cntT (S elements) -> off (block-local) + partials
// ---------------------------------------------------------------------------
__global__ __launch_bounds__(256) void k_scanA(const int* __restrict__ cntT,
                                               int* __restrict__ off,
                                               int* __restrict__ partials, int S) {
    __shared__ int sh[256];
    int tid = threadIdx.x;
    int base = blockIdx.x * 1024 + tid * 4;
    int v[4];
    int s = 0;
#pragma unroll
    for (int j = 0; j < 4; j++) {
        int idx = base + j;
        v[j] = (idx < S) ? cntT[idx] : 0;
        s += v[j];
    }
    sh[tid] = s;
    __syncthreads();
    int mysum = s;
    for (int o = 1; o < 256; o <<= 1) {
        int tv = (tid >= o) ? sh[tid - o] : 0;
        __syncthreads();
        sh[tid] += tv;
        __syncthreads();
    }
    int pref = sh[tid] - mysum;
#pragma unroll
    for (int j = 0; j < 4; j++) {
        int idx = base + j;
        if (idx < S) off[idx] = pref;
        pref += v[j];
    }
    if (tid == 255) partials[blockIdx.x] = sh[255];
}

__global__ void k_scanB(int* __restrict__ partials, int* __restrict__ off,
                        int nblk, int S) {
    if (blockIdx.x == 0 && threadIdx.x == 0) {
        int run = 0;
        for (int b = 0; b < nblk; b++) { int t = partials[b]; partials[b] = run; run += t; }
        off[S] = run;   // == E (absolute sentinel)
    }
}

// ---------------------------------------------------------------------------
// Pass 2: scatter edges into bucket-grouped ebuf. Entry = (src<<8)|(dst&255)
// (partial-add folded in: off[] is block-local, + partials[idx>>10])
// ---------------------------------------------------------------------------
__global__ __launch_bounds__(256) void k_sortwrite(const int* __restrict__ src,
                                                   const int* __restrict__ dst,
                                                   const int* __restrict__ off,
                                                   const int* __restrict__ partials,
                                                   int* __restrict__ ebuf,
                                                   int E, int NCH, int NBK) {
    __shared__ int cur[NBK_MAX];
    int t = threadIdx.x, c = blockIdx.x;
    for (int b = t; b < NBK; b += 256) {
        int idx = b * NCH + c;
        cur[b] = off[idx] + partials[idx >> 10];
    }
    __syncthreads();
    int base = c * CHUNK;
#pragma unroll 4
    for (int j = 0; j < CHUNK / 256; j++) {
        int e = base + j * 256 + t;
        if (e < E) {
            int s = src[e];
            int d = dst[e];
            int pos = atomicAdd(&cur[d >> BSH], 1);
            ebuf[pos] = (s << BSH) | (d & (BSPAN - 1));
        }
    }
}

// ---------------------------------------------------------------------------
// Pass 3: per-bucket node-level CSR: rp, dinv, node-sorted esrc (plain src)
// ---------------------------------------------------------------------------
__global__ __launch_bounds__(256) void k_bucket_csr(const int* __restrict__ off,
                                                    const int* __restrict__ partials,
                                                    const int* __restrict__ ebuf,
                                                    int* __restrict__ rp,
                                                    float* __restrict__ dinv,
                                                    int* __restrict__ esrc,
                                                    int N, int NCH, int NBK, int S) {
    __shared__ int cnt[BSPAN];
    __shared__ int sh[BSPAN];
    int b = blockIdx.x, t = threadIdx.x;
    int bi = b * NCH;
    int base = off[bi] + partials[bi >> 10];
    int ei_  = (b + 1) * NCH;
    int end  = (ei_ == S) ? off[S] : (off[ei_] + partials[ei_ >> 10]);

    cnt[t] = 0;
    __syncthreads();
    for (int i = base + t; i < end; i += 256) atomicAdd(&cnt[ebuf[i] & (BSPAN - 1)], 1);
    __syncthreads();

    int c = cnt[t];
    sh[t] = c;
    __syncthreads();
    for (int o = 1; o < 256; o <<= 1) {
        int tv = (t >= o) ? sh[t - o] : 0;
        __syncthreads();
        sh[t] += tv;
        __syncthreads();
    }
    int excl = sh[t] - c;

    int node = (b << BSH) + t;
    if (node < N) {
        rp[node] = base + excl;
        dinv[node] = rsqrtf((float)(1 + c));
    }
    if (b == NBK - 1) {
        if (t == 0) rp[N] = end;
        if (t < 16) esrc[end + t] = 0;     // pad (loads are clamped anyway)
    }
    __syncthreads();

    cnt[t] = base + excl;
    __syncthreads();
    for (int i = base + t; i < end; i += 256) {
        int v = ebuf[i];
        int p = atomicAdd(&cnt[v & (BSPAN - 1)], 1);
        esrc[p] = v >> BSH;                // plain src index
    }
}

// ---------------------------------------------------------------------------
// GEMM1 (K=256, A fp32): LDS staging via global_load_lds(16B), double-buffered,
// seg-rotation swizzle. Output fp16 (scaled by dinv[row]).
// ---------------------------------------------------------------------------
__global__ __launch_bounds__(256) void k_gemm1(const float* __restrict__ A,
                                               const __bf16* __restrict__ BfH,
                                               const __bf16* __restrict__ BfL,
                                               const float* __restrict__ dinv,
                                               _Float16* __restrict__ C, int nrows) {
    constexpr int K = 256, KC = 64, NCHK = 4, NCH32 = 8;
    __shared__ float As[2][64 * KC];       // 2 x 16 KB

    const int t = threadIdx.x;
    const int wave = t >> 6, lane = t & 63;
    const int m = lane & 15, q = lane >> 4;
    const int row0 = blockIdx.x * 64;

    const int s_sub = lane >> 4;
    const int s_seg = lane & 15;

    auto stage = [&](int ch, int buf) {
#pragma unroll
        for (int j = 0; j < 4; j++) {
            int lr = wave * 16 + j * 4 + s_sub;
            int gr = row0 + lr; if (gr > nrows - 1) gr = nrows - 1;
            int gs = (s_seg - lr) & 15;
            const float* g = A + (size_t)gr * K + ch * KC + gs * 4;
            float* l = &As[buf][(size_t)lr * KC + s_seg * 4];
            __builtin_amdgcn_global_load_lds(
                (const __attribute__((address_space(1))) void*)g,
                (__attribute__((address_space(3))) void*)l, 16, 0, 0);
        }
    };

    floatx4 acc[4] = {{0.f, 0.f, 0.f, 0.f}, {0.f, 0.f, 0.f, 0.f},
                      {0.f, 0.f, 0.f, 0.f}, {0.f, 0.f, 0.f, 0.f}};

    stage(0, 0);
    __syncthreads();

    for (int ch = 0; ch < NCHK; ch++) {
        if (ch + 1 < NCHK) stage(ch + 1, (ch + 1) & 1);

        const float* arow = &As[ch & 1][(size_t)(wave * 16 + m) * KC];
#pragma unroll
        for (int jj = 0; jj < 2; jj++) {
            int ch2 = ch * 2 + jj;
            int s0 = jj * 8 + q * 2;
            float4 v0 = *(const float4*)(arow + (((s0 + m) & 15) * 4));
            float4 v1 = *(const float4*)(arow + (((s0 + 1 + m) & 15) * 4));
            float af[8] = {v0.x, v0.y, v0.z, v0.w, v1.x, v1.y, v1.z, v1.w};
            bf16x8 ah, al;
#pragma unroll
            for (int j = 0; j < 8; j++) {
                __bf16 h = (__bf16)af[j];
                ah[j] = h;
                al[j] = (__bf16)(af[j] - (float)h);
            }
#pragma unroll
            for (int c = 0; c < 4; c++) {
                const bf16x8 bh = *(const bf16x8*)(BfH + ((size_t)(c * NCH32 + ch2) * 64 + lane) * 8);
                const bf16x8 bl = *(const bf16x8*)(BfL + ((size_t)(c * NCH32 + ch2) * 64 + lane) * 8);
                acc[c] = __builtin_amdgcn_mfma_f32_16x16x32_bf16(ah, bh, acc[c], 0, 0, 0);
                acc[c] = __builtin_amdgcn_mfma_f32_16x16x32_bf16(al, bh, acc[c], 0, 0, 0);
                acc[c] = __builtin_amdgcn_mfma_f32_16x16x32_bf16(ah, bl, acc[c], 0, 0, 0);
            }
        }
        __syncthreads();
    }

#pragma unroll
    for (int i = 0; i < 4; i++) {
        int r = row0 + wave * 16 + q * 4 + i;
        if (r < nrows) {
            float di = dinv[r];
#pragma unroll
            for (int c = 0; c < 4; c++)
                C[(size_t)r * 64 + c * 16 + m] = (_Float16)(acc[c][i] * di);
        }
    }
}

// ---------------------------------------------------------------------------
// GEMM2 (K=64, A fp16): single 8 KB LDS stage, split-bf16 MFMA. Output fp16.
// ---------------------------------------------------------------------------
__global__ __launch_bounds__(256) void k_gemm2(const _Float16* __restrict__ A,
                                               const __bf16* __restrict__ BfH,
                                               const __bf16* __restrict__ BfL,
                                               const float* __restrict__ dinv,
                                               _Float16* __restrict__ C, int nrows) {
    __shared__ _Float16 As[64 * 64];       // 8 KB
    const int t = threadIdx.x;
    const int wave = t >> 6, lane = t & 63;
    const int m = lane & 15, q = lane >> 4;
    const int row0 = blockIdx.x * 64;

#pragma unroll
    for (int j = 0; j < 2; j++) {
        int lr = j * 32 + wave * 8 + (lane >> 3);
        int p  = lane & 7;
        int gr = row0 + lr; if (gr > nrows - 1) gr = nrows - 1;
        int gs = (p - lr) & 7;                          // rotated seg
        const _Float16* g = A + (size_t)gr * 64 + gs * 8;
        _Float16* l = &As[(size_t)lr * 64 + p * 8];
        __builtin_amdgcn_global_load_lds(
            (const __attribute__((address_space(1))) void*)g,
            (__attribute__((address_space(3))) void*)l, 16, 0, 0);
    }
    __syncthreads();

    floatx4 acc[4] = {{0.f, 0.f, 0.f, 0.f}, {0.f, 0.f, 0.f, 0.f},
                      {0.f, 0.f, 0.f, 0.f}, {0.f, 0.f, 0.f, 0.f}};

    const _Float16* arow = &As[(size_t)(wave * 16 + m) * 64];
#pragma unroll
    for (int jj = 0; jj < 2; jj++) {
        int s0 = jj * 4 + q;
        half8 v = *(const half8*)(arow + (((s0 + m) & 7) * 8));
        bf16x8 ah, al;
#pragma unroll
        for (int j = 0; j < 8; j++) {
            float f = (float)v[j];
            __bf16 h = (__bf16)f;
            ah[j] = h;
            al[j] = (__bf16)(f - (float)h);
        }
#pragma unroll
        for (int c = 0; c < 4; c++) {
            const bf16x8 bh = *(const bf16x8*)(BfH + ((size_t)(c * 2 + jj) * 64 + lane) * 8);
            const bf16x8 bl = *(const bf16x8*)(BfL + ((size_t)(c * 2 + jj) * 64 + lane) * 8);
            acc[c] = __builtin_amdgcn_mfma_f32_16x16x32_bf16(ah, bh, acc[c], 0, 0, 0);
            acc[c] = __builtin_amdgcn_mfma_f32_16x16x32_bf16(al, bh, acc[c], 0, 0, 0);
            acc[c] = __builtin_amdgcn_mfma_f32_16x16x32_bf16(ah, bl, acc[c], 0, 0, 0);
        }
    }

#pragma unroll
    for (int i = 0; i < 4; i++) {
        int r = row0 + wave * 16 + q * 4 + i;
        if (r < nrows) {
            float di = dinv[r];
#pragma unroll
            for (int c = 0; c < 4; c++)
                C[(size_t)r * 64 + c * 16 + m] = (_Float16)(acc[c][i] * di);
        }
    }
}

// ---------------------------------------------------------------------------
// Aggregation over CSR: one wave per node, lane = (qe edge slot, fg feature
// group), half4v 8 B loads. 8-deep load block (32 edges/iter) pinned before
// accumulates with sched_barrier(0) — whole neighborhood of deg<=32 nodes
// (~96%) in flight at once. Clamped surplus gathers hit one L1 line (cheap).
// MODE 0: out[d] = relu fp16   MODE 1: h3[d] = (relu @ W3) * dinv[d] (fp32)
// ---------------------------------------------------------------------------
template <int MODE>
__global__ __launch_bounds__(256) void k_agg64(const _Float16* __restrict__ hs,
                                               const float* __restrict__ dinv,
                                               const int* __restrict__ rp,
                                               const int* __restrict__ esrc,
                                               const float* __restrict__ bias,
                                               const float* __restrict__ W3,
                                               void* __restrict__ out, int n) {
    int lane = threadIdx.x & 63;
    int qe = lane >> 4;          // edge slot 0..3
    int fg = lane & 15;          // feature group (4 consecutive feats)
    int nid = blockIdx.x * 4 + (threadIdx.x >> 6);
    if (nid >= n) return;
    nid = __builtin_amdgcn_readfirstlane(nid);

    float dii = dinv[nid];
    int e0 = rp[nid];
    int e1 = rp[nid + 1];
    int last = e1 - 1;

    float a0 = 0.f, a1 = 0.f, a2 = 0.f, a3 = 0.f;
    // self term (counted once: only edge-slot 0)
    if (qe == 0) {
        half4v sv = *(const half4v*)(hs + (size_t)nid * 64 + fg * 4);
        a0 = (float)sv[0]; a1 = (float)sv[1]; a2 = (float)sv[2]; a3 = (float)sv[3];
    }

    for (int e = e0; e <= last; e += 32) {
        // ---- load block: 8 esrc + 8 gathers, all issued before any use
        int idx[8];
#pragma unroll
        for (int u = 0; u < 8; u++)
            idx[u] = esrc[min(e + u * 4 + qe, last)];
        half4v v[8];
#pragma unroll
        for (int u = 0; u < 8; u++)
            v[u] = *(const half4v*)(hs + (size_t)idx[u] * 64 + fg * 4);
        __builtin_amdgcn_sched_barrier(0);   // pin: no accumulate hoists above
        // ---- accumulate block
#pragma unroll
        for (int u = 0; u < 8; u++) {
            if (e + u * 4 + qe <= last) {
                a0 += (float)v[u][0]; a1 += (float)v[u][1];
                a2 += (float)v[u][2]; a3 += (float)v[u][3];
            }
        }
    }

    // fold the 4 edge slots: after masks 16 and 32 every lane holds the sum
#pragma unroll
    for (int o = 16; o <= 32; o <<= 1) {
        a0 += __shfl_xor(a0, o, 64);
        a1 += __shfl_xor(a1, o, 64);
        a2 += __shfl_xor(a2, o, 64);
        a3 += __shfl_xor(a3, o, 64);
    }

    float4 b4 = ((const float4*)bias)[fg];
    a0 = fmaxf(a0 * dii + b4.x, 0.f);
    a1 = fmaxf(a1 * dii + b4.y, 0.f);
    a2 = fmaxf(a2 * dii + b4.z, 0.f);
    a3 = fmaxf(a3 * dii + b4.w, 0.f);

    if (MODE == 0) {
        if (qe == 0) {
            half4v o4;
            o4[0] = (_Float16)a0; o4[1] = (_Float16)a1;
            o4[2] = (_Float16)a2; o4[3] = (_Float16)a3;
            *(half4v*)((_Float16*)out + (size_t)nid * 64 + fg * 4) = o4;
        }
    } else {
        const float2* w3 = (const float2*)W3;
        float2 w0 = w3[fg * 4 + 0], w1 = w3[fg * 4 + 1];
        float2 w2 = w3[fg * 4 + 2], w3v = w3[fg * 4 + 3];
        float p0 = a0 * w0.x + a1 * w1.x + a2 * w2.x + a3 * w3v.x;
        float p1 = a0 * w0.y + a1 * w1.y + a2 * w2.y + a3 * w3v.y;
#pragma unroll
        for (int o = 1; o <= 8; o <<= 1) {
            p0 += __shfl_xor(p0, o, 64);
            p1 += __shfl_xor(p1, o, 64);
        }
        if (lane == 0) ((float2*)out)[nid] = make_float2(p0 * dii, p1 * dii);
    }
}

// ---------------------------------------------------------------------------
// Final layer: 2-wide aggregation + bias + log_softmax (thread per node).
// Loads issued as a pinned block (same sched_barrier trick as agg).
// ---------------------------------------------------------------------------
__global__ __launch_bounds__(256) void k_final(const float2* __restrict__ h3s,
                                               const float* __restrict__ dinv,
                                               const int* __restrict__ rp,
                                               const int* __restrict__ esrc,
                                               const float* __restrict__ b3,
                                               float* __restrict__ out, int n) {
    int i = blockIdx.x * blockDim.x + threadIdx.x;
    if (i >= n) return;
    float dii = dinv[i];
    float2 h = h3s[i];
    float ax = h.x, ay = h.y;
    float bx = 0.f, by = 0.f, cx = 0.f, cy = 0.f, dx = 0.f, dy = 0.f;
    int e0 = rp[i], e1 = rp[i + 1];
    int last = e1 - 1;
    for (int e = e0; e < e1; e += 4) {
        int s0 = esrc[min(e,     last)];
        int s1 = esrc[min(e + 1, last)];
        int s2 = esrc[min(e + 2, last)];
        int s3 = esrc[min(e + 3, last)];
        float2 v0 = h3s[s0];
        float2 v1 = h3s[s1];
        float2 v2 = h3s[s2];
        float2 v3 = h3s[s3];
        __builtin_amdgcn_sched_barrier(0);
        ax += v0.x; ay += v0.y;
        bx += (e + 1 <= last) ? v1.x : 0.f; by += (e + 1 <= last) ? v1.y : 0.f;
        cx += (e + 2 <= last) ? v2.x : 0.f; cy += (e + 2 <= last) ? v2.y : 0.f;
        dx += (e + 3 <= last) ? v3.x : 0.f; dy += (e + 3 <= last) ? v3.y : 0.f;
    }
    float l0 = ((ax + bx) + (cx + dx)) * dii + b3[0];
    float l1 = ((ay + by) + (cy + dy)) * dii + b3[1];
    float mx = fmaxf(l0, l1);
    float lse = mx + log1pf(__expf(-fabsf(l0 - l1)));
    ((float2*)out)[i] = make_float2(l0 - lse, l1 - lse);
}

// ---------------------------------------------------------------------------
// Launch
// ---------------------------------------------------------------------------
extern "C" void kernel_launch(void* const* d_in, const int* in_sizes, int n_in,
                              void* d_out, int out_size, void* d_ws, size_t ws_size,
                              hipStream_t stream) {
    const float* x   = (const float*)d_in[0];
    const int*   ei  = (const int*)d_in[1];
    const float* W1  = (const float*)d_in[2];
    const float* b1  = (const float*)d_in[3];
    const float* W2  = (const float*)d_in[4];
    const float* b2  = (const float*)d_in[5];
    const float* W3  = (const float*)d_in[6];
    const float* b3  = (const float*)d_in[7];
    float* out = (float*)d_out;

    const int N = in_sizes[0] / F_IN;   // 100000
    const int E = in_sizes[1] / 2;      // 1600000
    const int* src = ei;
    const int* dst = ei + E;

    const int NBK = (N + BSPAN - 1) / BSPAN;      // 391
    const int NCH = (E + CHUNK - 1) / CHUNK;      // 391
    const int S   = NBK * NCH;

    // workspace bump allocator (256B aligned)
    char* p = (char*)d_ws;
    auto alloc = [&](size_t bytes) -> void* {
        void* r = (void*)p;
        p += (bytes + 255) & ~(size_t)255;
        return r;
    };
    int*      cntT     = (int*)alloc((size_t)S * 4);
    int*      off      = (int*)alloc((size_t)(S + 1) * 4);
    int*      partials = (int*)alloc(4096);
    int*      ebuf     = (int*)alloc((size_t)E * 4);
    int*      esrc     = (int*)alloc((size_t)(E + 64) * 4);   // +pad
    int*      rp       = (int*)alloc((size_t)(N + 1) * 4);
    float*    dinv     = (float*)alloc((size_t)N * 4);
    _Float16* bufA     = (_Float16*)alloc((size_t)N * HID * 2);
    _Float16* bufB     = (_Float16*)alloc((size_t)N * HID * 2);
    float*    h3       = (float*)alloc((size_t)N * 2 * 4);
    __bf16*   f1h      = (__bf16*)alloc(16384 * 2);
    __bf16*   f1l      = (__bf16*)alloc(16384 * 2);
    __bf16*   f2h      = (__bf16*)alloc(4096 * 2);
    __bf16*   f2l      = (__bf16*)alloc(4096 * 2);

    const int T = 256;
    int scanBlocks = (S + 1023) / 1024;

    // CSR build (hist fused with weight prep); scanC folded into consumers
    k_pre<<<NCH, T, 0, stream>>>(dst, cntT, E, NCH, NBK, W1, f1h, f1l, W2, f2h, f2l);
    k_scanA<<<scanBlocks, T, 0, stream>>>(cntT, off, partials, S);
    k_scanB<<<1, 64, 0, stream>>>(partials, off, scanBlocks, S);
    k_sortwrite<<<NCH, T, 0, stream>>>(src, dst, off, partials, ebuf, E, NCH, NBK);
    k_bucket_csr<<<NBK, T, 0, stream>>>(off, partials, ebuf, rp, dinv, esrc, N, NCH, NBK, S);

    // layer 1
    int gemmBlocks = (N + 63) / 64;
    k_gemm1<<<gemmBlocks, T, 0, stream>>>(x, f1h, f1l, dinv, bufA, N);
    k_agg64<0><<<(N + 3) / 4, T, 0, stream>>>(bufA, dinv, rp, esrc, b1, nullptr, bufB, N);

    // layer 2 (+ fused GEMM3 in agg)
    k_gemm2<<<gemmBlocks, T, 0, stream>>>(bufB, f2h, f2l, dinv, bufA, N);
    k_agg64<1><<<(N + 3) / 4, T, 0, stream>>>(bufA, dinv, rp, esrc, b2, W3, h3, N);

    // layer 3 + log_softmax
    k_final<<<(N + T - 1) / T, T, 0, stream>>>((const float2*)h3, dinv, rp, esrc, b3, out, N);
}

// Round 11
// 360.580 us; speedup vs baseline: 1.4414x; 1.0368x over previous
//
#include <hip/hip_runtime.h>
#include <math.h>

#define F_IN 256
#define HID  64
#define BSH  8              // bucket = dst >> 8 (256 nodes per bucket)
#define BSPAN 256
#define CHUNK 4096          // edges per sort block (16 per thread)
#define NBK_MAX 512

typedef __bf16   bf16x8 __attribute__((ext_vector_type(8)));
typedef float    floatx4 __attribute__((ext_vector_type(4)));
typedef _Float16 half8 __attribute__((ext_vector_type(8)));
typedef _Float16 half4v __attribute__((ext_vector_type(4)));

// ---------------------------------------------------------------------------
// Fused pass: per-chunk histogram over coarse dst buckets + (blocks 0..7)
// weight prep W[K x 64] -> split-bf16 MFMA fragment layout.
// ---------------------------------------------------------------------------
__global__ __launch_bounds__(256) void k_pre(const int* __restrict__ dst,
                                             int* __restrict__ cntT,
                                             int E, int NCH, int NBK,
                                             const float* __restrict__ W1,
                                             __bf16* __restrict__ f1h, __bf16* __restrict__ f1l,
                                             const float* __restrict__ W2,
                                             __bf16* __restrict__ f2h, __bf16* __restrict__ f2l) {
    __shared__ int hist[NBK_MAX];
    int t = threadIdx.x, c = blockIdx.x;
    hist[t] = 0; hist[t + 256] = 0;
    __syncthreads();
    int base = c * CHUNK;
#pragma unroll 4
    for (int j = 0; j < CHUNK / 256; j++) {
        int e = base + j * 256 + t;
        if (e < E) atomicAdd(&hist[dst[e] >> BSH], 1);
    }
    __syncthreads();
    for (int b = t; b < NBK; b += 256) cntT[b * NCH + c] = hist[b];

    if (c < 8) {
        int g = c * 256 + t;                      // 0..2047
        for (int idx = g; idx < 16384; idx += 2048) {
            int j = idx & 7, lane = (idx >> 3) & 63, ch2 = (idx >> 9) & 7, cc = idx >> 12;
            int k = ch2 * 32 + (lane >> 4) * 8 + j, col = cc * 16 + (lane & 15);
            float w = W1[k * 64 + col];
            __bf16 h = (__bf16)w;
            f1h[idx] = h; f1l[idx] = (__bf16)(w - (float)h);
        }
        for (int idx = g; idx < 4096; idx += 2048) {
            int j = idx & 7, lane = (idx >> 3) & 63, ch2 = (idx >> 9) & 1, cc = idx >> 10;
            int k = ch2 * 32 + (lane >> 4) * 8 + j, col = cc * 16 + (lane & 15);
            float w = W2[k * 64 + col];
            __bf16 h = (__bf16)w;
            f2h[idx] = h; f2l[idx] = (__bf16)(w - (float)h);
        }
    }
}

// ---------------------------------------------------------------------------
// Exclusive scan of cntT (S elements) -> off (block-local) + partials
// ---------------------------------------------------------------------------
__global__ __launch_bounds__(256) void k_scanA(const int* __restrict__ cntT,
                                               int* __restrict__ off,
                                               int* __restrict__ partials, int S) {
    __shared__ int sh[256];
    int tid = threadIdx.x;
    int base = blockIdx.x * 1024 + tid * 4;
    int v[4];
    int s = 0;
#pragma unroll
    for (int j = 0; j < 4; j++) {
        int idx = base + j;
        v[j] = (idx < S) ? cntT[idx] : 0;
        s += v[j];
    }
    sh[tid] = s;
    __syncthreads();
    int mysum = s;
    for (int o = 1; o < 256; o <<= 1) {
        int tv = (tid >= o) ? sh[tid - o] : 0;
        __syncthreads();
        sh[tid] += tv;
        __syncthreads();
    }
    int pref = sh[tid] - mysum;
#pragma unroll
    for (int j = 0; j < 4; j++) {
        int idx = base + j;
        if (idx < S) off[idx] = pref;
        pref += v[j];
    }
    if (tid == 255) partials[blockIdx.x] = sh[255];
}

// ---------------------------------------------------------------------------
// Wave-parallel exclusive scan of partials (nblk <= ~1024): shfl_up + carry.
// Replaces the former serial single-thread loop (~150 dependent L2 RTs).
// ---------------------------------------------------------------------------
__global__ void k_scanB(int* __restrict__ partials, int* __restrict__ off,
                        int nblk, int S) {
    int lane = threadIdx.x;   // 64 lanes
    int carry = 0;
    for (int base = 0; base < nblk; base += 64) {
        int i = base + lane;
        int v = (i < nblk) ? partials[i] : 0;
        int x = v;
#pragma unroll
        for (int o = 1; o < 64; o <<= 1) {
            int t = __shfl_up(x, o, 64);
            if (lane >= o) x += t;
        }
        if (i < nblk) partials[i] = carry + x - v;   // exclusive
        carry += __shfl(x, 63, 64);
    }
    if (lane == 0) off[S] = carry;   // == E (absolute sentinel)
}

// ---------------------------------------------------------------------------
// Pass 2: scatter edges into bucket-grouped ebuf. Entry = (src<<8)|(dst&255)
// (partial-add folded in: off[] is block-local, + partials[idx>>10])
// ---------------------------------------------------------------------------
__global__ __launch_bounds__(256) void k_sortwrite(const int* __restrict__ src,
                                                   const int* __restrict__ dst,
                                                   const int* __restrict__ off,
                                                   const int* __restrict__ partials,
                                                   int* __restrict__ ebuf,
                                                   int E, int NCH, int NBK) {
    __shared__ int cur[NBK_MAX];
    int t = threadIdx.x, c = blockIdx.x;
    for (int b = t; b < NBK; b += 256) {
        int idx = b * NCH + c;
        cur[b] = off[idx] + partials[idx >> 10];
    }
    __syncthreads();
    int base = c * CHUNK;
#pragma unroll 4
    for (int j = 0; j < CHUNK / 256; j++) {
        int e = base + j * 256 + t;
        if (e < E) {
            int s = src[e];
            int d = dst[e];
            int pos = atomicAdd(&cur[d >> BSH], 1);
            ebuf[pos] = (s << BSH) | (d & (BSPAN - 1));
        }
    }
}

// ---------------------------------------------------------------------------
// Pass 3: per-bucket node-level CSR: rp, dinv, node-sorted esrc (plain src)
// ---------------------------------------------------------------------------
__global__ __launch_bounds__(256) void k_bucket_csr(const int* __restrict__ off,
                                                    const int* __restrict__ partials,
                                                    const int* __restrict__ ebuf,
                                                    int* __restrict__ rp,
                                                    float* __restrict__ dinv,
                                                    int* __restrict__ esrc,
                                                    int N, int NCH, int NBK, int S) {
    __shared__ int cnt[BSPAN];
    __shared__ int sh[BSPAN];
    int b = blockIdx.x, t = threadIdx.x;
    int bi = b * NCH;
    int base = off[bi] + partials[bi >> 10];
    int ei_  = (b + 1) * NCH;
    int end  = (ei_ == S) ? off[S] : (off[ei_] + partials[ei_ >> 10]);

    cnt[t] = 0;
    __syncthreads();
    for (int i = base + t; i < end; i += 256) atomicAdd(&cnt[ebuf[i] & (BSPAN - 1)], 1);
    __syncthreads();

    int c = cnt[t];
    sh[t] = c;
    __syncthreads();
    for (int o = 1; o < 256; o <<= 1) {
        int tv = (t >= o) ? sh[t - o] : 0;
        __syncthreads();
        sh[t] += tv;
        __syncthreads();
    }
    int excl = sh[t] - c;

    int node = (b << BSH) + t;
    if (node < N) {
        rp[node] = base + excl;
        dinv[node] = rsqrtf((float)(1 + c));
    }
    if (b == NBK - 1) {
        if (t == 0) rp[N] = end;
        if (t < 16) esrc[end + t] = 0;     // pad (loads are clamped anyway)
    }
    __syncthreads();

    cnt[t] = base + excl;
    __syncthreads();
    for (int i = base + t; i < end; i += 256) {
        int v = ebuf[i];
        int p = atomicAdd(&cnt[v & (BSPAN - 1)], 1);
        esrc[p] = v >> BSH;                // plain src index
    }
}

// ---------------------------------------------------------------------------
// GEMM1 (K=256, A fp32): LDS staging via global_load_lds(16B), double-buffered,
// seg-rotation swizzle. Output fp16 (scaled by dinv[row]).
// ---------------------------------------------------------------------------
__global__ __launch_bounds__(256) void k_gemm1(const float* __restrict__ A,
                                               const __bf16* __restrict__ BfH,
                                               const __bf16* __restrict__ BfL,
                                               const float* __restrict__ dinv,
                                               _Float16* __restrict__ C, int nrows) {
    constexpr int K = 256, KC = 64, NCHK = 4, NCH32 = 8;
    __shared__ float As[2][64 * KC];       // 2 x 16 KB

    const int t = threadIdx.x;
    const int wave = t >> 6, lane = t & 63;
    const int m = lane & 15, q = lane >> 4;
    const int row0 = blockIdx.x * 64;

    const int s_sub = lane >> 4;
    const int s_seg = lane & 15;

    auto stage = [&](int ch, int buf) {
#pragma unroll
        for (int j = 0; j < 4; j++) {
            int lr = wave * 16 + j * 4 + s_sub;
            int gr = row0 + lr; if (gr > nrows - 1) gr = nrows - 1;
            int gs = (s_seg - lr) & 15;
            const float* g = A + (size_t)gr * K + ch * KC + gs * 4;
            float* l = &As[buf][(size_t)lr * KC + s_seg * 4];
            __builtin_amdgcn_global_load_lds(
                (const __attribute__((address_space(1))) void*)g,
                (__attribute__((address_space(3))) void*)l, 16, 0, 0);
        }
    };

    floatx4 acc[4] = {{0.f, 0.f, 0.f, 0.f}, {0.f, 0.f, 0.f, 0.f},
                      {0.f, 0.f, 0.f, 0.f}, {0.f, 0.f, 0.f, 0.f}};

    stage(0, 0);
    __syncthreads();

    for (int ch = 0; ch < NCHK; ch++) {
        if (ch + 1 < NCHK) stage(ch + 1, (ch + 1) & 1);

        const float* arow = &As[ch & 1][(size_t)(wave * 16 + m) * KC];
#pragma unroll
        for (int jj = 0; jj < 2; jj++) {
            int ch2 = ch * 2 + jj;
            int s0 = jj * 8 + q * 2;
            float4 v0 = *(const float4*)(arow + (((s0 + m) & 15) * 4));
            float4 v1 = *(const float4*)(arow + (((s0 + 1 + m) & 15) * 4));
            float af[8] = {v0.x, v0.y, v0.z, v0.w, v1.x, v1.y, v1.z, v1.w};
            bf16x8 ah, al;
#pragma unroll
            for (int j = 0; j < 8; j++) {
                __bf16 h = (__bf16)af[j];
                ah[j] = h;
                al[j] = (__bf16)(af[j] - (float)h);
            }
#pragma unroll
            for (int c = 0; c < 4; c++) {
                const bf16x8 bh = *(const bf16x8*)(BfH + ((size_t)(c * NCH32 + ch2) * 64 + lane) * 8);
                const bf16x8 bl = *(const bf16x8*)(BfL + ((size_t)(c * NCH32 + ch2) * 64 + lane) * 8);
                acc[c] = __builtin_amdgcn_mfma_f32_16x16x32_bf16(ah, bh, acc[c], 0, 0, 0);
                acc[c] = __builtin_amdgcn_mfma_f32_16x16x32_bf16(al, bh, acc[c], 0, 0, 0);
                acc[c] = __builtin_amdgcn_mfma_f32_16x16x32_bf16(ah, bl, acc[c], 0, 0, 0);
            }
        }
        __syncthreads();
    }

#pragma unroll
    for (int i = 0; i < 4; i++) {
        int r = row0 + wave * 16 + q * 4 + i;
        if (r < nrows) {
            float di = dinv[r];
#pragma unroll
            for (int c = 0; c < 4; c++)
                C[(size_t)r * 64 + c * 16 + m] = (_Float16)(acc[c][i] * di);
        }
    }
}

// ---------------------------------------------------------------------------
// GEMM2 (K=64, A fp16): single 8 KB LDS stage, split-bf16 MFMA. Output fp16.
// ---------------------------------------------------------------------------
__global__ __launch_bounds__(256) void k_gemm2(const _Float16* __restrict__ A,
                                               const __bf16* __restrict__ BfH,
                                               const __bf16* __restrict__ BfL,
                                               const float* __restrict__ dinv,
                                               _Float16* __restrict__ C, int nrows) {
    __shared__ _Float16 As[64 * 64];       // 8 KB
    const int t = threadIdx.x;
    const int wave = t >> 6, lane = t & 63;
    const int m = lane & 15, q = lane >> 4;
    const int row0 = blockIdx.x * 64;

#pragma unroll
    for (int j = 0; j < 2; j++) {
        int lr = j * 32 + wave * 8 + (lane >> 3);
        int p  = lane & 7;
        int gr = row0 + lr; if (gr > nrows - 1) gr = nrows - 1;
        int gs = (p - lr) & 7;                          // rotated seg
        const _Float16* g = A + (size_t)gr * 64 + gs * 8;
        _Float16* l = &As[(size_t)lr * 64 + p * 8];
        __builtin_amdgcn_global_load_lds(
            (const __attribute__((address_space(1))) void*)g,
            (__attribute__((address_space(3))) void*)l, 16, 0, 0);
    }
    __syncthreads();

    floatx4 acc[4] = {{0.f, 0.f, 0.f, 0.f}, {0.f, 0.f, 0.f, 0.f},
                      {0.f, 0.f, 0.f, 0.f}, {0.f, 0.f, 0.f, 0.f}};

    const _Float16* arow = &As[(size_t)(wave * 16 + m) * 64];
#pragma unroll
    for (int jj = 0; jj < 2; jj++) {
        int s0 = jj * 4 + q;
        half8 v = *(const half8*)(arow + (((s0 + m) & 7) * 8));
        bf16x8 ah, al;
#pragma unroll
        for (int j = 0; j < 8; j++) {
            float f = (float)v[j];
            __bf16 h = (__bf16)f;
            ah[j] = h;
            al[j] = (__bf16)(f - (float)h);
        }
#pragma unroll
        for (int c = 0; c < 4; c++) {
            const bf16x8 bh = *(const bf16x8*)(BfH + ((size_t)(c * 2 + jj) * 64 + lane) * 8);
            const bf16x8 bl = *(const bf16x8*)(BfL + ((size_t)(c * 2 + jj) * 64 + lane) * 8);
            acc[c] = __builtin_amdgcn_mfma_f32_16x16x32_bf16(ah, bh, acc[c], 0, 0, 0);
            acc[c] = __builtin_amdgcn_mfma_f32_16x16x32_bf16(al, bh, acc[c], 0, 0, 0);
            acc[c] = __builtin_amdgcn_mfma_f32_16x16x32_bf16(ah, bl, acc[c], 0, 0, 0);
        }
    }

#pragma unroll
    for (int i = 0; i < 4; i++) {
        int r = row0 + wave * 16 + q * 4 + i;
        if (r < nrows) {
            float di = dinv[r];
#pragma unroll
            for (int c = 0; c < 4; c++)
                C[(size_t)r * 64 + c * 16 + m] = (_Float16)(acc[c][i] * di);
        }
    }
}

// ---------------------------------------------------------------------------
// Aggregation over CSR: one wave per node, lane = (qe=lane>>3 edge slot 0..7,
// f8=lane&7 feature octet). half8 16 B/lane gathers: 8 edges per wave
// instruction (2x fewer VMEM instrs + TA addresses than half4v). 4-deep load
// block (32 edges/iter) pinned before accumulates with sched_barrier(0).
// Fold over slots = shfl_xor {8,16,32}.
// MODE 0: out[d] = relu fp16   MODE 1: h3[d] = (relu @ W3) * dinv[d] (fp32)
// ---------------------------------------------------------------------------
template <int MODE>
__global__ __launch_bounds__(256) void k_agg64(const _Float16* __restrict__ hs,
                                               const float* __restrict__ dinv,
                                               const int* __restrict__ rp,
                                               const int* __restrict__ esrc,
                                               const float* __restrict__ bias,
                                               const float* __restrict__ W3,
                                               void* __restrict__ out, int n) {
    int lane = threadIdx.x & 63;
    int qe = lane >> 3;          // edge slot 0..7
    int f8 = lane & 7;           // feature octet (8 halves = 16 B)
    int nid = blockIdx.x * 4 + (threadIdx.x >> 6);
    if (nid >= n) return;
    nid = __builtin_amdgcn_readfirstlane(nid);

    float dii = dinv[nid];
    int e0 = rp[nid];
    int e1 = rp[nid + 1];
    int last = e1 - 1;

    float a0 = 0.f, a1 = 0.f, a2 = 0.f, a3 = 0.f;
    float a4 = 0.f, a5 = 0.f, a6 = 0.f, a7 = 0.f;
    // self term (counted once: only edge-slot 0)
    if (qe == 0) {
        half8 sv = *(const half8*)(hs + (size_t)nid * 64 + f8 * 8);
        a0 = (float)sv[0]; a1 = (float)sv[1]; a2 = (float)sv[2]; a3 = (float)sv[3];
        a4 = (float)sv[4]; a5 = (float)sv[5]; a6 = (float)sv[6]; a7 = (float)sv[7];
    }

    for (int e = e0; e <= last; e += 32) {
        // ---- load block: 4 esrc + 4 gathers (8 edges each), issued first
        int idx[4];
#pragma unroll
        for (int u = 0; u < 4; u++)
            idx[u] = esrc[min(e + u * 8 + qe, last)];
        half8 v[4];
#pragma unroll
        for (int u = 0; u < 4; u++)
            v[u] = *(const half8*)(hs + (size_t)idx[u] * 64 + f8 * 8);
        __builtin_amdgcn_sched_barrier(0);   // pin: no accumulate hoists above
        // ---- accumulate block
#pragma unroll
        for (int u = 0; u < 4; u++) {
            if (e + u * 8 + qe <= last) {
                a0 += (float)v[u][0]; a1 += (float)v[u][1];
                a2 += (float)v[u][2]; a3 += (float)v[u][3];
                a4 += (float)v[u][4]; a5 += (float)v[u][5];
                a6 += (float)v[u][6]; a7 += (float)v[u][7];
            }
        }
    }

    // fold the 8 edge slots (qe bits = lane bits 3..5)
#pragma unroll
    for (int o = 8; o <= 32; o <<= 1) {
        a0 += __shfl_xor(a0, o, 64);
        a1 += __shfl_xor(a1, o, 64);
        a2 += __shfl_xor(a2, o, 64);
        a3 += __shfl_xor(a3, o, 64);
        a4 += __shfl_xor(a4, o, 64);
        a5 += __shfl_xor(a5, o, 64);
        a6 += __shfl_xor(a6, o, 64);
        a7 += __shfl_xor(a7, o, 64);
    }

    float4 b0 = ((const float4*)bias)[f8 * 2];
    float4 b1 = ((const float4*)bias)[f8 * 2 + 1];
    a0 = fmaxf(a0 * dii + b0.x, 0.f);
    a1 = fmaxf(a1 * dii + b0.y, 0.f);
    a2 = fmaxf(a2 * dii + b0.z, 0.f);
    a3 = fmaxf(a3 * dii + b0.w, 0.f);
    a4 = fmaxf(a4 * dii + b1.x, 0.f);
    a5 = fmaxf(a5 * dii + b1.y, 0.f);
    a6 = fmaxf(a6 * dii + b1.z, 0.f);
    a7 = fmaxf(a7 * dii + b1.w, 0.f);

    if (MODE == 0) {
        if (qe == 0) {
            half8 o8;
            o8[0] = (_Float16)a0; o8[1] = (_Float16)a1;
            o8[2] = (_Float16)a2; o8[3] = (_Float16)a3;
            o8[4] = (_Float16)a4; o8[5] = (_Float16)a5;
            o8[6] = (_Float16)a6; o8[7] = (_Float16)a7;
            *(half8*)((_Float16*)out + (size_t)nid * 64 + f8 * 8) = o8;
        }
    } else {
        const float2* w3 = (const float2*)W3;
        float2 w0 = w3[f8 * 8 + 0], w1 = w3[f8 * 8 + 1];
        float2 w2 = w3[f8 * 8 + 2], w3v = w3[f8 * 8 + 3];
        float2 w4 = w3[f8 * 8 + 4], w5 = w3[f8 * 8 + 5];
        float2 w6 = w3[f8 * 8 + 6], w7 = w3[f8 * 8 + 7];
        float p0 = a0 * w0.x + a1 * w1.x + a2 * w2.x + a3 * w3v.x
                 + a4 * w4.x + a5 * w5.x + a6 * w6.x + a7 * w7.x;
        float p1 = a0 * w0.y + a1 * w1.y + a2 * w2.y + a3 * w3v.y
                 + a4 * w4.y + a5 * w5.y + a6 * w6.y + a7 * w7.y;
#pragma unroll
        for (int o = 1; o <= 4; o <<= 1) {
            p0 += __shfl_xor(p0, o, 64);
            p1 += __shfl_xor(p1, o, 64);
        }
        if (lane == 0) ((float2*)out)[nid] = make_float2(p0 * dii, p1 * dii);
    }
}

// ---------------------------------------------------------------------------
// Final layer: 2-wide aggregation + bias + log_softmax (thread per node).
// Loads issued as a pinned block (same sched_barrier trick as agg).
// ---------------------------------------------------------------------------
__global__ __launch_bounds__(256) void k_final(const float2* __restrict__ h3s,
                                               const float* __restrict__ dinv,
                                               const int* __restrict__ rp,
                                               const int* __restrict__ esrc,
                                               const float* __restrict__ b3,
                                               float* __restrict__ out, int n) {
    int i = blockIdx.x * blockDim.x + threadIdx.x;
    if (i >= n) return;
    float dii = dinv[i];
    float2 h = h3s[i];
    float ax = h.x, ay = h.y;
    float bx = 0.f, by = 0.f, cx = 0.f, cy = 0.f, dx = 0.f, dy = 0.f;
    int e0 = rp[i], e1 = rp[i + 1];
    int last = e1 - 1;
    for (int e = e0; e < e1; e += 4) {
        int s0 = esrc[min(e,     last)];
        int s1 = esrc[min(e + 1, last)];
        int s2 = esrc[min(e + 2, last)];
        int s3 = esrc[min(e + 3, last)];
        float2 v0 = h3s[s0];
        float2 v1 = h3s[s1];
        float2 v2 = h3s[s2];
        float2 v3 = h3s[s3];
        __builtin_amdgcn_sched_barrier(0);
        ax += v0.x; ay += v0.y;
        bx += (e + 1 <= last) ? v1.x : 0.f; by += (e + 1 <= last) ? v1.y : 0.f;
        cx += (e + 2 <= last) ? v2.x : 0.f; cy += (e + 2 <= last) ? v2.y : 0.f;
        dx += (e + 3 <= last) ? v3.x : 0.f; dy += (e + 3 <= last) ? v3.y : 0.f;
    }
    float l0 = ((ax + bx) + (cx + dx)) * dii + b3[0];
    float l1 = ((ay + by) + (cy + dy)) * dii + b3[1];
    float mx = fmaxf(l0, l1);
    float lse = mx + log1pf(__expf(-fabsf(l0 - l1)));
    ((float2*)out)[i] = make_float2(l0 - lse, l1 - lse);
}

// ---------------------------------------------------------------------------
// Launch
// ---------------------------------------------------------------------------
extern "C" void kernel_launch(void* const* d_in, const int* in_sizes, int n_in,
                              void* d_out, int out_size, void* d_ws, size_t ws_size,
                              hipStream_t stream) {
    const float* x   = (const float*)d_in[0];
    const int*   ei  = (const int*)d_in[1];
    const float* W1  = (const float*)d_in[2];
    const float* b1  = (const float*)d_in[3];
    const float* W2  = (const float*)d_in[4];
    const float* b2  = (const float*)d_in[5];
    const float* W3  = (const float*)d_in[6];
    const float* b3  = (const float*)d_in[7];
    float* out = (float*)d_out;

    const int N = in_sizes[0] / F_IN;   // 100000
    const int E = in_sizes[1] / 2;      // 1600000
    const int* src = ei;
    const int* dst = ei + E;

    const int NBK = (N + BSPAN - 1) / BSPAN;      // 391
    const int NCH = (E + CHUNK - 1) / CHUNK;      // 391
    const int S   = NBK * NCH;

    // workspace bump allocator (256B aligned)
    char* p = (char*)d_ws;
    auto alloc = [&](size_t bytes) -> void* {
        void* r = (void*)p;
        p += (bytes + 255) & ~(size_t)255;
        return r;
    };
    int*      cntT     = (int*)alloc((size_t)S * 4);
    int*      off      = (int*)alloc((size_t)(S + 1) * 4);
    int*      partials = (int*)alloc(4096);
    int*      ebuf     = (int*)alloc((size_t)E * 4);
    int*      esrc     = (int*)alloc((size_t)(E + 64) * 4);   // +pad
    int*      rp       = (int*)alloc((size_t)(N + 1) * 4);
    float*    dinv     = (float*)alloc((size_t)N * 4);
    _Float16* bufA     = (_Float16*)alloc((size_t)N * HID * 2);
    _Float16* bufB     = (_Float16*)alloc((size_t)N * HID * 2);
    float*    h3       = (float*)alloc((size_t)N * 2 * 4);
    __bf16*   f1h      = (__bf16*)alloc(16384 * 2);
    __bf16*   f1l      = (__bf16*)alloc(16384 * 2);
    __bf16*   f2h      = (__bf16*)alloc(4096 * 2);
    __bf16*   f2l      = (__bf16*)alloc(4096 * 2);

    const int T = 256;
    int scanBlocks = (S + 1023) / 1024;

    // CSR build (hist fused with weight prep); scanC folded into consumers
    k_pre<<<NCH, T, 0, stream>>>(dst, cntT, E, NCH, NBK, W1, f1h, f1l, W2, f2h, f2l);
    k_scanA<<<scanBlocks, T, 0, stream>>>(cntT, off, partials, S);
    k_scanB<<<1, 64, 0, stream>>>(partials, off, scanBlocks, S);
    k_sortwrite<<<NCH, T, 0, stream>>>(src, dst, off, partials, ebuf, E, NCH, NBK);
    k_bucket_csr<<<NBK, T, 0, stream>>>(off, partials, ebuf, rp, dinv, esrc, N, NCH, NBK, S);

    // layer 1
    int gemmBlocks = (N + 63) / 64;
    k_gemm1<<<gemmBlocks, T, 0, stream>>>(x, f1h, f1l, dinv, bufA, N);
    k_agg64<0><<<(N + 3) / 4, T, 0, stream>>>(bufA, dinv, rp, esrc, b1, nullptr, bufB, N);

    // layer 2 (+ fused GEMM3 in agg)
    k_gemm2<<<gemmBlocks, T, 0, stream>>>(bufB, f2h, f2l, dinv, bufA, N);
    k_agg64<1><<<(N + 3) / 4, T, 0, stream>>>(bufA, dinv, rp, esrc, b2, W3, h3, N);

    // layer 3 + log_softmax
    k_final<<<(N + T - 1) / T, T, 0, stream>>>((const float2*)h3, dinv, rp, esrc, b3, out, N);
}